// Round 13
// baseline (3382.581 us; speedup 1.0000x reference)
//
#include <hip/hip_runtime.h>

// ---------------------------------------------------------------------------
// HeteroSimplexLayer on MI355X (gfx950).
// v6: = v5 + vectorized GEMM epilogue (LDS f32 transpose -> 8x16B stores per
// thread instead of 64x2B scalar stores; aux reads coalesced) + A-S erf
// replacing libm erff in GELU. K-loop (depth-2 ring, counted vmcnt) and all
// other kernels unchanged for attribution.
// ---------------------------------------------------------------------------

#define NNODES 100000
#define NPAD   100096          // 782 tiles of 128
#define DIM    256
#define NREL   4
#define NTRI   150000

typedef unsigned short ushortT;
typedef __attribute__((ext_vector_type(8)))  short   short8;
typedef __attribute__((ext_vector_type(4)))  float   floatx4;
typedef __attribute__((ext_vector_type(4)))  unsigned short ushort4v;

__device__ __forceinline__ float bf2f(ushortT u) {
    union { unsigned int i; float f; } c; c.i = ((unsigned int)u) << 16; return c.f;
}
__device__ __forceinline__ ushortT f2bf(float f) {
    union { float f; unsigned int i; } c; c.f = f;
    unsigned int x = c.i;
    x += 0x7fffu + ((x >> 16) & 1u);      // RNE
    return (ushortT)(x >> 16);
}
// Abramowitz-Stegun 7.1.26, |err| < 1.5e-7 (exact at bf16 output precision)
__device__ __forceinline__ float erf_as(float x) {
    float ax = fabsf(x);
    float k  = 1.0f / (1.0f + 0.3275911f * ax);
    float p  = k * (0.254829592f + k * (-0.284496736f + k * (1.421413741f +
               k * (-1.453152027f + k * 1.061405429f))));
    float r  = 1.0f - p * __expf(-ax * ax);
    return copysignf(r, x);
}

// -------------------------------- small kernels ----------------------------

__global__ void cvt_f32_bf16(const float* __restrict__ in, ushortT* __restrict__ out, int n4) {
    int i = blockIdx.x * blockDim.x + threadIdx.x;
    int stride = gridDim.x * blockDim.x;
    for (; i < n4; i += stride) {
        float4 v = ((const float4*)in)[i];
        ushort4v o; o.x = f2bf(v.x); o.y = f2bf(v.y); o.z = f2bf(v.z); o.w = f2bf(v.w);
        ((ushort4v*)out)[i] = o;
    }
}

// W_comb[r][o][k] = sum_j tri_W[r][o][j] * node_W[r][j][k]
__global__ void wcomb_kernel(const float* __restrict__ nodeW, const float* __restrict__ triW,
                             ushortT* __restrict__ wcomb) {
    int idx = blockIdx.x * 256 + threadIdx.x;       // r*65536 + o*256 + k
    int r = idx >> 16, o = (idx >> 8) & 255, k = idx & 255;
    const float* tw = triW  + ((size_t)r << 16) + o * 256;
    const float* nw = nodeW + ((size_t)r << 16) + k;
    float s = 0.f;
    #pragma unroll 8
    for (int j = 0; j < 256; ++j) s += tw[j] * nw[(size_t)j * 256];
    wcomb[idx] = f2bf(s);
}

// xgW[512][256]: rows 0..255 = res_W rows; rows 256..511 = gate_W[:, :256] rows
__global__ void pack_xg(const float* __restrict__ resW, const float* __restrict__ gateW,
                        ushortT* __restrict__ o) {
    int idx = blockIdx.x * 256 + threadIdx.x;       // 512*256
    int r = idx >> 8, k = idx & 255;
    float v = (r < 256) ? resW[r * 256 + k] : gateW[(size_t)(r - 256) * 512 + k];
    o[idx] = f2bf(v);
}

// Wvo[512][256]: rows 0..255 = outW[:, :128] @ inW[512:640]; rows 256..511 hi half
__global__ void pack_wvo(const float* __restrict__ outW, const float* __restrict__ inW,
                         ushortT* __restrict__ o) {
    int idx = blockIdx.x * 256 + threadIdx.x;       // 512*256
    int r = idx >> 8, k = idx & 255;
    int orow = r & 255, d0 = (r >> 8) * 128;
    float s = 0.f;
    #pragma unroll 8
    for (int j = 0; j < 128; ++j)
        s += outW[orow * 256 + d0 + j] * inW[(size_t)(512 + d0 + j) * 256 + k];
    o[idx] = f2bf(s);
}

// bvo[c] = per-half fold of in_b[512:768] through outW (out_b added in combine)
__global__ void calc_bvo(const float* __restrict__ outW, const float* __restrict__ in_b,
                         float* __restrict__ bvo) {
    int c = blockIdx.x * 256 + threadIdx.x;         // 512
    int orow = c & 255, d0 = (c >> 8) * 128;
    float s = 0.f;
    #pragma unroll 8
    for (int j = 0; j < 128; ++j) s += outW[orow * 256 + d0 + j] * in_b[512 + d0 + j];
    bvo[c] = s;
}

// ---------------- CSR build, batched over relations (blockIdx.y = r) -------

__global__ void k_count4(const int* __restrict__ tri, int* __restrict__ cnt4, int n3) {
    int r = blockIdx.y;
    int i = blockIdx.x * 256 + threadIdx.x;
    if (i < n3) atomicAdd(&cnt4[r * NPAD + tri[(size_t)r * n3 + i]], 1);
}

__global__ void k_scan1(const int* __restrict__ cnt4, int* __restrict__ ptr4,
                        int* __restrict__ bsum4, int n) {
    int r = blockIdx.y;
    const int* cnt = cnt4 + r * NPAD;
    int* ptr = ptr4 + r * NPAD;
    int* bsum = bsum4 + r * 512;
    __shared__ int s[256];
    int i = blockIdx.x * 256 + threadIdx.x;
    int v = (i < n) ? cnt[i] : 0;
    s[threadIdx.x] = v; __syncthreads();
    for (int off = 1; off < 256; off <<= 1) {
        int t = (threadIdx.x >= off) ? s[threadIdx.x - off] : 0;
        __syncthreads();
        s[threadIdx.x] += t;
        __syncthreads();
    }
    if (i < n) ptr[i] = s[threadIdx.x] - v;            // block-local exclusive
    if (threadIdx.x == 255) bsum[blockIdx.x] = s[255];
}

__global__ void k_scan2(const int* __restrict__ bsum4, int* __restrict__ bpre4, int nb) {
    int r = blockIdx.x;
    const int* bsum = bsum4 + r * 512;
    int* bpre = bpre4 + r * 512;
    int lane = threadIdx.x & 63;
    int run = 0;
    for (int c = 0; c < nb; c += 64) {
        int idx = c + lane;
        int v = (idx < nb) ? bsum[idx] : 0;
        int incl = v;
        #pragma unroll
        for (int off = 1; off < 64; off <<= 1) {
            int t = __shfl_up(incl, off, 64);
            if (lane >= off) incl += t;
        }
        if (idx < nb) bpre[idx] = run + incl - v;
        run += __shfl(incl, 63, 64);
    }
}

__global__ void k_scan3(const int* __restrict__ bpre4, int* __restrict__ ptr4,
                        int* __restrict__ cur4, int n) {
    int r = blockIdx.y;
    int i = blockIdx.x * 256 + threadIdx.x;
    if (i < n) {
        int p = ptr4[r * NPAD + i] + bpre4[r * 512 + blockIdx.x];
        ptr4[r * NPAD + i] = p; cur4[r * NPAD + i] = p;
    }
}

__global__ void k_fill4(const int* __restrict__ tri, int* __restrict__ cur4,
                        int* __restrict__ adj4, int n3, int T) {
    int r = blockIdx.y;
    int i = blockIdx.x * 256 + threadIdx.x;
    if (i >= n3) return;
    int node = tri[(size_t)r * n3 + i];
    int t = i; if (t >= 2 * T) t -= 2 * T; else if (t >= T) t -= T;
    int pos = atomicAdd(&cur4[r * NPAD + node], 1);
    adj4[(size_t)r * n3 + pos] = t;
}

// meanx[t] = (x[a]+x[b]+x[c])/3 as bf16 row (reads pre-converted bf16 x)
__global__ __launch_bounds__(256)
void k_meanx(const int* __restrict__ tri, const ushortT* __restrict__ xb,
             ushortT* __restrict__ mx, int T) {
    int t = blockIdx.x * 4 + (threadIdx.x >> 6);
    if (t >= T) return;
    int lane = threadIdx.x & 63;
    int a = tri[t], b = tri[T + t], c = tri[2 * T + t];
    ushort4v va = *(const ushort4v*)(xb + (size_t)a * DIM + lane * 4);
    ushort4v vb = *(const ushort4v*)(xb + (size_t)b * DIM + lane * 4);
    ushort4v vc = *(const ushort4v*)(xb + (size_t)c * DIM + lane * 4);
    ushort4v o;
    o.x = f2bf((bf2f(va.x) + bf2f(vb.x) + bf2f(vc.x)) * (1.0f / 3.0f));
    o.y = f2bf((bf2f(va.y) + bf2f(vb.y) + bf2f(vc.y)) * (1.0f / 3.0f));
    o.z = f2bf((bf2f(va.z) + bf2f(vb.z) + bf2f(vc.z)) * (1.0f / 3.0f));
    o.w = f2bf((bf2f(va.w) + bf2f(vb.w) + bf2f(vc.w)) * (1.0f / 3.0f));
    *(ushort4v*)(mx + (size_t)t * DIM + lane * 4) = o;
}

// acc_bf[n] = (sum over incident triangles of meanx[t]) / max(cnt,1)
__global__ __launch_bounds__(256)
void k_gather(const int* __restrict__ ptr, const int* __restrict__ cnt,
              const int* __restrict__ adj, const ushortT* __restrict__ mx,
              ushortT* __restrict__ accb, int n) {
    int node = blockIdx.x * 4 + (threadIdx.x >> 6);
    if (node >= n) return;
    int lane = threadIdx.x & 63;
    int st = ptr[node], c = cnt[node];
    float a0 = 0.f, a1 = 0.f, a2 = 0.f, a3 = 0.f;
    for (int j = 0; j < c; ++j) {
        int t = adj[st + j];
        ushort4v v = *(const ushort4v*)(mx + (size_t)t * DIM + lane * 4);
        a0 += bf2f(v.x); a1 += bf2f(v.y); a2 += bf2f(v.z); a3 += bf2f(v.w);
    }
    float inv = 1.0f / fmaxf((float)c, 1.0f);
    ushort4v o; o.x = f2bf(a0 * inv); o.y = f2bf(a1 * inv);
    o.z = f2bf(a2 * inv); o.w = f2bf(a3 * inv);
    *(ushort4v*)(accb + (size_t)node * DIM + lane * 4) = o;
}

// -------------------------------- GEMM -------------------------------------
// C[m, col] = sum_k A[m,k] * W[col,k]. 128x128 tile, BK=32, 4 waves (2x2),
// each wave 64x64 via 4x4 MFMA 16x16x32 bf16. blockIdx.z batches relations.
// K-loop: depth-2 prefetch via 3-buffer LDS ring, counted vmcnt(4).
// Epilogue: acc staged through f32 LDS (128x133 pad) -> each thread owns one
// row-half (64 consecutive cols) -> 8x 16B stores, coalesced aux reads.

#define BK 32
#define PADW 133                // 133*4B: bank base 5r mod 32 -> 32 rows distinct

__device__ __forceinline__ void async_cp16(char* lds, const char* glb) {
    __builtin_amdgcn_global_load_lds((const __attribute__((address_space(1))) unsigned int*)glb,
                                     (__attribute__((address_space(3))) unsigned int*)lds,
                                     16, 0, 0);
}

enum { M_BF16 = 0, M_ELU = 1, M_GATE = 2, M_QKV = 3, M_RES = 4, M_GELU = 5 };

template <int MODE>
__global__ __launch_bounds__(256)
void gemm_bt(const ushortT* __restrict__ A, int lda, size_t aStrZ,
             const ushortT* __restrict__ W, int ldw, size_t wStrZ,
             int M, int K,
             ushortT* __restrict__ outB, int ldo, size_t oStrZ,
             const float* __restrict__ bias,
             const ushortT* __restrict__ aux1,    // GATE: Gx (z-shared)
             const ushortT* __restrict__ aux2,    // GATE: xres (z-shared)
             int auxLd,
             const ushortT* __restrict__ resB,    // RES: residual row (bf16)
             size_t resStrZ) {
    const size_t zi = blockIdx.z;
    A += zi * aStrZ; W += zi * wStrZ;
    if (outB) outB += zi * oStrZ;
    if (resB) resB += zi * resStrZ;

    // union: K-loop ring (A 3x8KB @0, B 3x8KB @24576) | epilogue f32 tile
    __shared__ __align__(16) char smem[128 * PADW * 4];   // 68096 B
    const int tid  = threadIdx.x;
    const int wave = tid >> 6, lane = tid & 63;
    const int m0 = blockIdx.y * 128;
    const int n0 = blockIdx.x * 128;
    const int wm = (wave >> 1) * 64, wn = (wave & 1) * 64;

    floatx4 acc[4][4];
    #pragma unroll
    for (int i = 0; i < 4; ++i)
        #pragma unroll
        for (int j = 0; j < 4; ++j) acc[i][j] = (floatx4){0.f, 0.f, 0.f, 0.f};

    const int r4  = tid >> 2;            // row within 64-row chunk
    const int b16 = (tid & 3) * 16;      // byte offset in 64B row slice
    const char* Ab = (const char*)A + ((size_t)(m0 + r4) * lda) * 2 + b16;
    const char* Wb = (const char*)W + ((size_t)(n0 + r4) * ldw) * 2 + b16;

    const int kq = (lane >> 4) * 8;
    const int ra = wm + (lane & 15);
    const int rb = wn + (lane & 15);

    auto stage = [&](int buf, int k0) {
        char* Asl = smem + buf * 8192 + wave * 1024;          // wave-uniform base
        char* Bsl = smem + 24576 + buf * 8192 + wave * 1024;
        async_cp16(Asl,        Ab + k0 * 2);
        async_cp16(Asl + 4096, Ab + k0 * 2 + (size_t)64 * lda * 2);
        async_cp16(Bsl,        Wb + k0 * 2);
        async_cp16(Bsl + 4096, Wb + k0 * 2 + (size_t)64 * ldw * 2);
    };
    auto compute = [&](int buf) {
        const ushortT* Abuf = (const ushortT*)(smem + buf * 8192);
        const ushortT* Bbuf = (const ushortT*)(smem + 24576 + buf * 8192);
        short8 af[4], bfr[4];
        #pragma unroll
        for (int i = 0; i < 4; ++i) {
            af[i]  = *(const short8*)(Abuf + (ra + i * 16) * BK + kq);
            bfr[i] = *(const short8*)(Bbuf + (rb + i * 16) * BK + kq);
        }
        #pragma unroll
        for (int mi = 0; mi < 4; ++mi)
            #pragma unroll
            for (int ni = 0; ni < 4; ++ni)
                acc[mi][ni] = __builtin_amdgcn_mfma_f32_16x16x32_bf16(af[mi], bfr[ni], acc[mi][ni], 0, 0, 0);
    };

    const int NIT = K / BK;              // 8 or 16
    stage(0, 0);
    stage(1, BK);                        // 8 loads in flight
    asm volatile("s_waitcnt vmcnt(4)" ::: "memory");   // stage0 done
    __builtin_amdgcn_s_barrier();

    int bufc = 0, bufs = 2;
    for (int it = 0; it < NIT; ++it) {
        if (it + 2 < NIT) stage(bufs, (it + 2) * BK);   // keep 2 stages in flight
        compute(bufc);
        if (it + 1 < NIT) {
            if (it + 2 < NIT) asm volatile("s_waitcnt vmcnt(4)" ::: "memory");
            else              asm volatile("s_waitcnt vmcnt(0)" ::: "memory");
            __builtin_amdgcn_s_barrier();
        }
        bufc = (bufc == 2) ? 0 : bufc + 1;
        bufs = (bufs == 2) ? 0 : bufs + 1;
    }

    // ---- epilogue: f32 LDS transpose -> vectorized row stores ----
    __syncthreads();                     // all waves done with ring buffers
    float* Ct = (float*)smem;
    const int cl = lane & 15, rw = (lane >> 4) * 4;
    #pragma unroll
    for (int mi = 0; mi < 4; ++mi)
        #pragma unroll
        for (int ni = 0; ni < 4; ++ni)
            #pragma unroll
            for (int e = 0; e < 4; ++e)
                Ct[(wm + mi * 16 + rw + e) * PADW + (wn + ni * 16 + cl)] = acc[mi][ni][e];
    __syncthreads();

    const int row = tid >> 1;            // 0..127
    const int cb  = (tid & 1) * 64;      // col half within tile
    const int m   = m0 + row;
    if (m < M) {
        #pragma unroll
        for (int k8 = 0; k8 < 8; ++k8) {
            const int c0  = cb + k8 * 8;
            const int col = n0 + c0;     // global col, multiple of 8
            float v[8];
            #pragma unroll
            for (int j = 0; j < 8; ++j) v[j] = Ct[row * PADW + c0 + j];
            short8 ov;
            if (MODE == M_BF16) {
                #pragma unroll
                for (int j = 0; j < 8; ++j) ov[j] = (short)f2bf(v[j]);
            } else if (MODE == M_ELU) {
                #pragma unroll
                for (int j = 0; j < 8; ++j) {
                    float c = v[j] > 0.f ? v[j] : (__expf(v[j]) - 1.0f);
                    ov[j] = (short)f2bf(c);
                }
            } else if (MODE == M_GATE) {
                short8 gv = *(const short8*)(aux1 + (size_t)m * auxLd + col);
                short8 xv = *(const short8*)(aux2 + (size_t)m * auxLd + col);
                short8 uv = *(const short8*)(A + (size_t)m * lda + col);
                #pragma unroll
                for (int j = 0; j < 8; ++j) {
                    float g  = bf2f((ushortT)gv[j]);
                    float xr = bf2f((ushortT)xv[j]);
                    float u  = bf2f((ushortT)uv[j]);
                    float a  = 1.0f / (1.0f + __expf(-(v[j] + g + bias[col + j])));
                    float th = 1.0f - 2.0f / (__expf(2.0f * u) + 1.0f);
                    ov[j] = (short)f2bf(th * a + xr * (1.0f - a));
                }
            } else if (MODE == M_QKV) {
                #pragma unroll
                for (int j = 0; j < 8; ++j) ov[j] = (short)f2bf(v[j] + bias[col + j]);
            } else if (MODE == M_RES) {
                short8 rv = *(const short8*)(resB + (size_t)m * 256 + col);
                #pragma unroll
                for (int j = 0; j < 8; ++j)
                    ov[j] = (short)f2bf(v[j] + bias[col + j] + bf2f((ushortT)rv[j]));
            } else if (MODE == M_GELU) {
                #pragma unroll
                for (int j = 0; j < 8; ++j) {
                    float t = v[j] + bias[col + j];
                    ov[j] = (short)f2bf(0.5f * t * (1.0f + erf_as(t * 0.70710678118f)));
                }
            }
            *(short8*)(&outB[(size_t)m * ldo + col]) = ov;
        }
    }
}

// ------------------------------ attention ----------------------------------
__global__ __launch_bounds__(256)
void attn_score(const ushortT* __restrict__ qk, size_t rstride,
                float* __restrict__ Aw, int nvalid) {
    int n = blockIdx.x * 4 + (threadIdx.x >> 6);
    if (n >= nvalid) return;
    int lane = threadIdx.x & 63;
    int head = lane >> 5, hl = lane & 31;
    int d = head * 128 + hl * 4;
    float q[NREL][4], k[NREL][4];
    #pragma unroll
    for (int r = 0; r < NREL; ++r) {
        const ushortT* base = qk + r * rstride + (size_t)n * 512;
        ushort4v qv = *(const ushort4v*)(base + d);
        ushort4v kv = *(const ushort4v*)(base + 256 + d);
        q[r][0] = bf2f(qv.x); q[r][1] = bf2f(qv.y); q[r][2] = bf2f(qv.z); q[r][3] = bf2f(qv.w);
        k[r][0] = bf2f(kv.x); k[r][1] = bf2f(kv.y); k[r][2] = bf2f(kv.z); k[r][3] = bf2f(kv.w);
    }
    float s[NREL][NREL];
    #pragma unroll
    for (int qr = 0; qr < NREL; ++qr)
        #pragma unroll
        for (int kr = 0; kr < NREL; ++kr) {
            float p = q[qr][0] * k[kr][0] + q[qr][1] * k[kr][1] +
                      q[qr][2] * k[kr][2] + q[qr][3] * k[kr][3];
            #pragma unroll
            for (int off = 1; off < 32; off <<= 1) p += __shfl_xor(p, off, 32);
            s[qr][kr] = p * 0.08838834764831845f;   // 1/sqrt(128)
        }
    if (hl < 16) {
        int qr = hl >> 2, kr = hl & 3;
        float mx = fmaxf(fmaxf(s[qr][0], s[qr][1]), fmaxf(s[qr][2], s[qr][3]));
        float e0 = __expf(s[qr][0] - mx), e1 = __expf(s[qr][1] - mx);
        float e2 = __expf(s[qr][2] - mx), e3 = __expf(s[qr][3] - mx);
        float e  = __expf(s[qr][kr] - mx);
        Aw[((size_t)n * 2 + head) * 16 + qr * 4 + kr] = e / (e0 + e1 + e2 + e3);
    }
}

// z[qr,n,:] = h[qr,n,:] + out_b + sum_kr (A0*vo_lo[kr] + A1*vo_hi[kr]);
// x1[qr] = LN1(z).  One wave per node, fully in-register + shfl reductions.
__global__ __launch_bounds__(256)
void attn_combine_ln1(const ushortT* __restrict__ vo4, size_t rstride,
                      const ushortT* __restrict__ h4, size_t hstride,
                      const float* __restrict__ Aw,
                      const float* __restrict__ ob,
                      const float* __restrict__ g, const float* __restrict__ b,
                      ushortT* __restrict__ x1, size_t x1str, int nvalid) {
    int n = blockIdx.x * 4 + (threadIdx.x >> 6);
    if (n >= nvalid) return;
    int lane = threadIdx.x & 63;
    int d4 = lane * 4;
    const float* ap = Aw + (size_t)n * 32;
    float a0[NREL][NREL], a1[NREL][NREL];
    #pragma unroll
    for (int qr = 0; qr < NREL; ++qr)
        #pragma unroll
        for (int kr = 0; kr < NREL; ++kr) {
            a0[qr][kr] = ap[qr * 4 + kr];
            a1[qr][kr] = ap[16 + qr * 4 + kr];
        }
    float vl[NREL][4], vh[NREL][4];
    #pragma unroll
    for (int kr = 0; kr < NREL; ++kr) {
        const ushortT* base = vo4 + kr * rstride + (size_t)n * 512;
        ushort4v lo = *(const ushort4v*)(base + d4);
        ushort4v hi = *(const ushort4v*)(base + 256 + d4);
        vl[kr][0] = bf2f(lo.x); vl[kr][1] = bf2f(lo.y); vl[kr][2] = bf2f(lo.z); vl[kr][3] = bf2f(lo.w);
        vh[kr][0] = bf2f(hi.x); vh[kr][1] = bf2f(hi.y); vh[kr][2] = bf2f(hi.z); vh[kr][3] = bf2f(hi.w);
    }
    float bb0 = ob[d4], bb1 = ob[d4 + 1], bb2 = ob[d4 + 2], bb3 = ob[d4 + 3];
    float g0 = g[d4], g1 = g[d4 + 1], g2 = g[d4 + 2], g3 = g[d4 + 3];
    float e0 = b[d4], e1 = b[d4 + 1], e2 = b[d4 + 2], e3 = b[d4 + 3];
    #pragma unroll
    for (int qr = 0; qr < NREL; ++qr) {
        ushort4v hv = *(const ushort4v*)(h4 + qr * hstride + (size_t)n * 256 + d4);
        float z0 = bf2f(hv.x) + bb0, z1 = bf2f(hv.y) + bb1;
        float z2 = bf2f(hv.z) + bb2, z3 = bf2f(hv.w) + bb3;
        #pragma unroll
        for (int kr = 0; kr < NREL; ++kr) {
            float c0 = a0[qr][kr], c1 = a1[qr][kr];
            z0 += c0 * vl[kr][0] + c1 * vh[kr][0];
            z1 += c0 * vl[kr][1] + c1 * vh[kr][1];
            z2 += c0 * vl[kr][2] + c1 * vh[kr][2];
            z3 += c0 * vl[kr][3] + c1 * vh[kr][3];
        }
        float s = z0 + z1 + z2 + z3;
        #pragma unroll
        for (int off = 1; off < 64; off <<= 1) s += __shfl_xor(s, off, 64);
        float mean = s * (1.0f / 256.0f);
        float dx = z0 - mean, dy = z1 - mean, dz = z2 - mean, dw = z3 - mean;
        float qs = dx * dx + dy * dy + dz * dz + dw * dw;
        #pragma unroll
        for (int off = 1; off < 64; off <<= 1) qs += __shfl_xor(qs, off, 64);
        float rstd = rsqrtf(qs * (1.0f / 256.0f) + 1e-5f);
        ushort4v o;
        o.x = f2bf(dx * rstd * g0 + e0); o.y = f2bf(dy * rstd * g1 + e1);
        o.z = f2bf(dz * rstd * g2 + e2); o.w = f2bf(dw * rstd * g3 + e3);
        *(ushort4v*)(x1 + qr * x1str + (size_t)n * 256 + d4) = o;
    }
}

// out[row] = 0.25 * sum_r LN2(zb[r][row]).  zb is bf16; written exactly once.
__global__ __launch_bounds__(256)
void ln2_out(const ushortT* __restrict__ zb, size_t zStrZ,
             const float* __restrict__ g, const float* __restrict__ b,
             float* __restrict__ outc, int n) {
    int row = blockIdx.x * 4 + (threadIdx.x >> 6);
    if (row >= n) return;
    int lane = threadIdx.x & 63, c0 = lane * 4;
    float g0 = g[c0], g1 = g[c0 + 1], g2 = g[c0 + 2], g3 = g[c0 + 3];
    float b0 = b[c0], b1 = b[c0 + 1], b2 = b[c0 + 2], b3 = b[c0 + 3];
    float o0 = 0.f, o1 = 0.f, o2 = 0.f, o3 = 0.f;
    #pragma unroll
    for (int r = 0; r < NREL; ++r) {
        ushort4v v = *(const ushort4v*)(zb + r * zStrZ + (size_t)row * 256 + c0);
        float vx = bf2f(v.x), vy = bf2f(v.y), vz = bf2f(v.z), vw = bf2f(v.w);
        float s = vx + vy + vz + vw;
        #pragma unroll
        for (int off = 1; off < 64; off <<= 1) s += __shfl_xor(s, off, 64);
        float mean = s * (1.0f / 256.0f);
        float dx = vx - mean, dy = vy - mean, dz = vz - mean, dw = vw - mean;
        float qs = dx * dx + dy * dy + dz * dz + dw * dw;
        #pragma unroll
        for (int off = 1; off < 64; off <<= 1) qs += __shfl_xor(qs, off, 64);
        float rstd = rsqrtf(qs * (1.0f / 256.0f) + 1e-5f);
        o0 += 0.25f * (dx * rstd * g0 + b0);
        o1 += 0.25f * (dy * rstd * g1 + b1);
        o2 += 0.25f * (dz * rstd * g2 + b2);
        o3 += 0.25f * (dw * rstd * g3 + b3);
    }
    float4 o; o.x = o0; o.y = o1; o.z = o2; o.w = o3;
    *(float4*)(outc + (size_t)row * 256 + c0) = o;
}

// ------------------------------ host ---------------------------------------

extern "C" void kernel_launch(void* const* d_in, const int* in_sizes, int n_in,
                              void* d_out, int out_size, void* d_ws, size_t ws_size,
                              hipStream_t stream) {
    const float* x      = (const float*)d_in[0];
    const int*   tri    = (const int*)d_in[1];
    const float* nodeW  = (const float*)d_in[3];
    const float* triW   = (const float*)d_in[4];
    const float* resW   = (const float*)d_in[5];
    const float* gateW  = (const float*)d_in[6];
    const float* gate_b = (const float*)d_in[7];
    const float* inW    = (const float*)d_in[8];
    const float* in_b   = (const float*)d_in[9];
    const float* outW   = (const float*)d_in[10];
    const float* out_b  = (const float*)d_in[11];
    const float* ln1g   = (const float*)d_in[12];
    const float* ln1b   = (const float*)d_in[13];
    const float* lin1W  = (const float*)d_in[14];
    const float* lin1b  = (const float*)d_in[15];
    const float* lin2W  = (const float*)d_in[16];
    const float* lin2b  = (const float*)d_in[17];
    const float* ln2g   = (const float*)d_in[18];
    const float* ln2b   = (const float*)d_in[19];
    float* out = (float*)d_out;

    // ---------------- persistent workspace ----------------
    char* ws = (char*)d_ws;
    size_t off = 0;
    auto alloc = [&](size_t bytes) -> char* {
        char* p = ws + off; off += (bytes + 255) & ~(size_t)255; return p;
    };
    ushortT* accAll  = (ushortT*)alloc((size_t)NREL * NPAD * 256 * 2);  // 205 MB
    ushortT* xall_b  = (ushortT*)alloc((size_t)NPAD * 256 * 2);         // 51 MB
    ushortT* wcomb   = (ushortT*)alloc((size_t)NREL * 65536 * 2);
    ushortT* xgW_b   = (ushortT*)alloc((size_t)131072 * 2);
    ushortT* gateW_b = (ushortT*)alloc((size_t)131072 * 2);
    ushortT* inW_b   = (ushortT*)alloc((size_t)131072 * 2);             // qk rows only
    ushortT* wvo_b   = (ushortT*)alloc((size_t)131072 * 2);
    ushortT* lin1_bf = (ushortT*)alloc((size_t)131072 * 2);
    ushortT* lin2_bf = (ushortT*)alloc((size_t)131072 * 2);
    float*   bvo     = (float*)  alloc((size_t)512 * 4);
    size_t persist = off;
    size_t scratch = (ws_size > persist) ? (ws_size - persist) : 0;
    char* S = ws + persist;

    // scatter-phase scratch (dead before chunk phase): batched CSR + meanx
    int*     cnt4  = (int*)(S);                            // 4*NPAD
    int*     ptr4  = cnt4 + 4 * NPAD;
    int*     cur4  = ptr4 + 4 * NPAD;
    int*     bsum4 = cur4 + 4 * NPAD;                      // 4*512
    int*     bpre4 = bsum4 + 4 * 512;
    int*     adj4  = bpre4 + 4 * 512;                      // 4*3*NTRI
    size_t csrBytes = ((char*)(adj4 + (size_t)4 * 3 * NTRI) - S + 255) & ~(size_t)255;
    const size_t mxBytes = (size_t)NTRI * 256 * 2;         // 77 MB
    if (scratch < csrBytes + mxBytes + 65536) return;
    ushortT* mxbf = (ushortT*)(S + csrBytes);

    // chunk scratch: 9344 B/row (phase-aliased layout, zb in bf16)
    const size_t ROWB = 9344;
    int TT = (NNODES + 127) / 128;              // 782
    int tpcMax = (int)(scratch / (ROWB * 128));
    if (tpcMax < 1) return;
    if (tpcMax > TT) tpcMax = TT;
    const int nchunks = (TT + tpcMax - 1) / tpcMax;
    const int tpc = (TT + nchunks - 1) / nchunks;       // balanced chunks
    const size_t NcPad = (size_t)tpc * 128;

    // chunk layout (byte-offset/row):
    //   A: xg@0 (1024) | ubf4@1024 (2048) | h4@3072 (2048)
    //   B: qk4@5120 (4096) | Aw@9216 (128) | vo4 alias qk4 | x1@0 (2048)
    //   C: ffg@2048 (4096) | zbb@6144 (2048, bf16)
    ushortT* xg   = (ushortT*)(S);
    ushortT* ubf4 = (ushortT*)(S + 1024 * NcPad);
    ushortT* h4   = (ushortT*)(S + 3072 * NcPad);
    ushortT* qk4  = (ushortT*)(S + 5120 * NcPad);
    ushortT* vo4  = qk4;
    ushortT* x1   = (ushortT*)(S);
    ushortT* ffg  = (ushortT*)(S + 2048 * NcPad);
    ushortT* zbb  = (ushortT*)(S + 6144 * NcPad);
    float*   Aw   = (float*)  (S + 9216 * NcPad);

    // ---------------- weights to bf16 + folds ----------------
    cvt_f32_bf16<<<2048, 256, 0, stream>>>(x, xall_b, NNODES * 64);
    cvt_f32_bf16<<<64, 256, 0, stream>>>(gateW, gateW_b, 131072 / 4);
    cvt_f32_bf16<<<64, 256, 0, stream>>>(inW,   inW_b,   131072 / 4);
    cvt_f32_bf16<<<64, 256, 0, stream>>>(lin1W, lin1_bf, 131072 / 4);
    cvt_f32_bf16<<<64, 256, 0, stream>>>(lin2W, lin2_bf, 131072 / 4);
    pack_xg<<<512, 256, 0, stream>>>(resW, gateW, xgW_b);
    pack_wvo<<<512, 256, 0, stream>>>(outW, inW, wvo_b);
    calc_bvo<<<2, 256, 0, stream>>>(outW, in_b, bvo);
    wcomb_kernel<<<1024, 256, 0, stream>>>(nodeW, triW, wcomb);

    // ---------------- scatter phase: batched CSR, per-relation gather ------
    const int NB = (NNODES + 255) / 256;        // 391 scan blocks
    const int N3B = (3 * NTRI + 255) / 256;
    (void)hipMemsetAsync(cnt4, 0, (size_t)4 * NPAD * 4, stream);
    k_count4<<<dim3(N3B, 4), 256, 0, stream>>>(tri, cnt4, 3 * NTRI);
    k_scan1<<<dim3(NB, 4), 256, 0, stream>>>(cnt4, ptr4, bsum4, NNODES);
    k_scan2<<<4, 64, 0, stream>>>(bsum4, bpre4, NB);
    k_scan3<<<dim3(NB, 4), 256, 0, stream>>>(bpre4, ptr4, cur4, NNODES);
    k_fill4<<<dim3(N3B, 4), 256, 0, stream>>>(tri, cur4, adj4, 3 * NTRI, NTRI);
    for (int r = 0; r < NREL; ++r) {
        const int* trir = tri + (size_t)r * 3 * NTRI;
        k_meanx<<<(NTRI + 3) / 4, 256, 0, stream>>>(trir, xall_b, mxbf, NTRI);
        k_gather<<<(NNODES + 3) / 4, 256, 0, stream>>>(
            ptr4 + (size_t)r * NPAD, cnt4 + (size_t)r * NPAD,
            adj4 + (size_t)r * 3 * NTRI, mxbf,
            accAll + (size_t)r * NPAD * 256, NNODES);
    }

    // ---------------- chunked main pipeline ----------------
    for (int ci = 0; ci < nchunks; ++ci) {
        const int rows0 = ci * tpc * 128;
        int mact = NNODES - rows0;
        if (mact <= 0) break;
        if (mact > tpc * 128) mact = tpc * 128;
        const int tiles = (mact + 127) / 128;
        const dim3 g2z(2, tiles, NREL), g4z(4, tiles, NREL);
        const int nwblk = (mact + 3) / 4;
        float* outc = out + (size_t)rows0 * 256;
        const ushortT* xbf = xall_b + (size_t)rows0 * 256;

        // xg = [x@res_W.T | x@gate_W[:, :D].T]  (N=512, packed weight)
        gemm_bt<M_BF16><<<dim3(4, tiles), 256, 0, stream>>>(xbf, 256, 0, xgW_b, 256, 0, mact, 256,
            xg, 512, 0, nullptr, nullptr, nullptr, 0, nullptr, 0);
        // u[r] = elu(acc[r] @ W_comb[r].T)
        gemm_bt<M_ELU><<<g2z, 256, 0, stream>>>(
            accAll + (size_t)rows0 * 256, 256, (size_t)NPAD * 256,
            wcomb, 256, 65536, mact, 256,
            ubf4, 256, 256 * NcPad, nullptr, nullptr, nullptr, 0, nullptr, 0);
        // a = sigmoid(u@gW2.T + Gx + b); h = tanh(u)*a + xres*(1-a)
        gemm_bt<M_GATE><<<g2z, 256, 0, stream>>>(
            ubf4, 256, 256 * NcPad, gateW_b + 256, 512, 0, mact, 256,
            h4, 256, 256 * NcPad, gate_b, xg + 256, xg, 512, nullptr, 0);
        // qk[r] = h[r] @ in_W[0:512].T + b
        gemm_bt<M_QKV><<<g4z, 256, 0, stream>>>(
            h4, 256, 256 * NcPad, inW_b, 256, 0, mact, 256,
            qk4, 512, 512 * NcPad, in_b, nullptr, nullptr, 0, nullptr, 0);
        attn_score<<<nwblk, 256, 0, stream>>>(qk4, 512 * NcPad, Aw, mact);
        // vo[r] = h[r] @ Wvo.T + bvo   (out_W folded; qk region dead)
        gemm_bt<M_QKV><<<g4z, 256, 0, stream>>>(
            h4, 256, 256 * NcPad, wvo_b, 256, 0, mact, 256,
            vo4, 512, 512 * NcPad, bvo, nullptr, nullptr, 0, nullptr, 0);
        // z = h + combine(A, vo) + out_b ; x1 = LN1(z)   (fused, in-register)
        attn_combine_ln1<<<nwblk, 256, 0, stream>>>(vo4, 512 * NcPad, h4, 256 * NcPad,
            Aw, out_b, ln1g, ln1b, x1, 256 * NcPad, mact);
        // ffg = gelu(x1 @ lin1_W.T + b)
        gemm_bt<M_GELU><<<g4z, 256, 0, stream>>>(x1, 256, 256 * NcPad, lin1_bf, 256, 0, mact, 256,
            ffg, 512, 512 * NcPad, lin1b, nullptr, nullptr, 0, nullptr, 0);
        // z = x1 + ffg @ lin2_W.T + b   (bf16 out)
        gemm_bt<M_RES><<<g2z, 256, 0, stream>>>(ffg, 512, 512 * NcPad, lin2_bf, 512, 0, mact, 512,
            zbb, 256, 256 * NcPad, lin2b, nullptr, nullptr, 0, x1, 256 * NcPad);
        // out = 0.25 * sum_r LN2(z[r])
        ln2_out<<<nwblk, 256, 0, stream>>>(zbb, 256 * NcPad, ln2g, ln2b, outc, mact);
    }
}

// Round 14
// 3210.775 us; speedup vs baseline: 1.0535x; 1.0535x over previous
//
#include <hip/hip_runtime.h>

// ---------------------------------------------------------------------------
// HeteroSimplexLayer on MI355X (gfx950).
// v7: = v6 but the vectorized epilogue runs in TWO 64-row passes through a
// 64x133 f32 LDS tile (34 KB) inside the 48 KB ring union -> LDS stays
// 49152 B -> 3 blocks/CU (v6's 68 KB tile dropped occupancy to 2, a net
// regression). A-S erf retained. All else unchanged from v5/v6.
// ---------------------------------------------------------------------------

#define NNODES 100000
#define NPAD   100096          // 782 tiles of 128
#define DIM    256
#define NREL   4
#define NTRI   150000

typedef unsigned short ushortT;
typedef __attribute__((ext_vector_type(8)))  short   short8;
typedef __attribute__((ext_vector_type(4)))  float   floatx4;
typedef __attribute__((ext_vector_type(4)))  unsigned short ushort4v;

__device__ __forceinline__ float bf2f(ushortT u) {
    union { unsigned int i; float f; } c; c.i = ((unsigned int)u) << 16; return c.f;
}
__device__ __forceinline__ ushortT f2bf(float f) {
    union { float f; unsigned int i; } c; c.f = f;
    unsigned int x = c.i;
    x += 0x7fffu + ((x >> 16) & 1u);      // RNE
    return (ushortT)(x >> 16);
}
// Abramowitz-Stegun 7.1.26, |err| < 1.5e-7 (exact at bf16 output precision)
__device__ __forceinline__ float erf_as(float x) {
    float ax = fabsf(x);
    float k  = 1.0f / (1.0f + 0.3275911f * ax);
    float p  = k * (0.254829592f + k * (-0.284496736f + k * (1.421413741f +
               k * (-1.453152027f + k * 1.061405429f))));
    float r  = 1.0f - p * __expf(-ax * ax);
    return copysignf(r, x);
}

// -------------------------------- small kernels ----------------------------

__global__ void cvt_f32_bf16(const float* __restrict__ in, ushortT* __restrict__ out, int n4) {
    int i = blockIdx.x * blockDim.x + threadIdx.x;
    int stride = gridDim.x * blockDim.x;
    for (; i < n4; i += stride) {
        float4 v = ((const float4*)in)[i];
        ushort4v o; o.x = f2bf(v.x); o.y = f2bf(v.y); o.z = f2bf(v.z); o.w = f2bf(v.w);
        ((ushort4v*)out)[i] = o;
    }
}

// W_comb[r][o][k] = sum_j tri_W[r][o][j] * node_W[r][j][k]
__global__ void wcomb_kernel(const float* __restrict__ nodeW, const float* __restrict__ triW,
                             ushortT* __restrict__ wcomb) {
    int idx = blockIdx.x * 256 + threadIdx.x;       // r*65536 + o*256 + k
    int r = idx >> 16, o = (idx >> 8) & 255, k = idx & 255;
    const float* tw = triW  + ((size_t)r << 16) + o * 256;
    const float* nw = nodeW + ((size_t)r << 16) + k;
    float s = 0.f;
    #pragma unroll 8
    for (int j = 0; j < 256; ++j) s += tw[j] * nw[(size_t)j * 256];
    wcomb[idx] = f2bf(s);
}

// xgW[512][256]: rows 0..255 = res_W rows; rows 256..511 = gate_W[:, :256] rows
__global__ void pack_xg(const float* __restrict__ resW, const float* __restrict__ gateW,
                        ushortT* __restrict__ o) {
    int idx = blockIdx.x * 256 + threadIdx.x;       // 512*256
    int r = idx >> 8, k = idx & 255;
    float v = (r < 256) ? resW[r * 256 + k] : gateW[(size_t)(r - 256) * 512 + k];
    o[idx] = f2bf(v);
}

// Wvo[512][256]: rows 0..255 = outW[:, :128] @ inW[512:640]; rows 256..511 hi half
__global__ void pack_wvo(const float* __restrict__ outW, const float* __restrict__ inW,
                         ushortT* __restrict__ o) {
    int idx = blockIdx.x * 256 + threadIdx.x;       // 512*256
    int r = idx >> 8, k = idx & 255;
    int orow = r & 255, d0 = (r >> 8) * 128;
    float s = 0.f;
    #pragma unroll 8
    for (int j = 0; j < 128; ++j)
        s += outW[orow * 256 + d0 + j] * inW[(size_t)(512 + d0 + j) * 256 + k];
    o[idx] = f2bf(s);
}

// bvo[c] = per-half fold of in_b[512:768] through outW (out_b added in combine)
__global__ void calc_bvo(const float* __restrict__ outW, const float* __restrict__ in_b,
                         float* __restrict__ bvo) {
    int c = blockIdx.x * 256 + threadIdx.x;         // 512
    int orow = c & 255, d0 = (c >> 8) * 128;
    float s = 0.f;
    #pragma unroll 8
    for (int j = 0; j < 128; ++j) s += outW[orow * 256 + d0 + j] * in_b[512 + d0 + j];
    bvo[c] = s;
}

// ---------------- CSR build, batched over relations (blockIdx.y = r) -------

__global__ void k_count4(const int* __restrict__ tri, int* __restrict__ cnt4, int n3) {
    int r = blockIdx.y;
    int i = blockIdx.x * 256 + threadIdx.x;
    if (i < n3) atomicAdd(&cnt4[r * NPAD + tri[(size_t)r * n3 + i]], 1);
}

__global__ void k_scan1(const int* __restrict__ cnt4, int* __restrict__ ptr4,
                        int* __restrict__ bsum4, int n) {
    int r = blockIdx.y;
    const int* cnt = cnt4 + r * NPAD;
    int* ptr = ptr4 + r * NPAD;
    int* bsum = bsum4 + r * 512;
    __shared__ int s[256];
    int i = blockIdx.x * 256 + threadIdx.x;
    int v = (i < n) ? cnt[i] : 0;
    s[threadIdx.x] = v; __syncthreads();
    for (int off = 1; off < 256; off <<= 1) {
        int t = (threadIdx.x >= off) ? s[threadIdx.x - off] : 0;
        __syncthreads();
        s[threadIdx.x] += t;
        __syncthreads();
    }
    if (i < n) ptr[i] = s[threadIdx.x] - v;            // block-local exclusive
    if (threadIdx.x == 255) bsum[blockIdx.x] = s[255];
}

__global__ void k_scan2(const int* __restrict__ bsum4, int* __restrict__ bpre4, int nb) {
    int r = blockIdx.x;
    const int* bsum = bsum4 + r * 512;
    int* bpre = bpre4 + r * 512;
    int lane = threadIdx.x & 63;
    int run = 0;
    for (int c = 0; c < nb; c += 64) {
        int idx = c + lane;
        int v = (idx < nb) ? bsum[idx] : 0;
        int incl = v;
        #pragma unroll
        for (int off = 1; off < 64; off <<= 1) {
            int t = __shfl_up(incl, off, 64);
            if (lane >= off) incl += t;
        }
        if (idx < nb) bpre[idx] = run + incl - v;
        run += __shfl(incl, 63, 64);
    }
}

__global__ void k_scan3(const int* __restrict__ bpre4, int* __restrict__ ptr4,
                        int* __restrict__ cur4, int n) {
    int r = blockIdx.y;
    int i = blockIdx.x * 256 + threadIdx.x;
    if (i < n) {
        int p = ptr4[r * NPAD + i] + bpre4[r * 512 + blockIdx.x];
        ptr4[r * NPAD + i] = p; cur4[r * NPAD + i] = p;
    }
}

__global__ void k_fill4(const int* __restrict__ tri, int* __restrict__ cur4,
                        int* __restrict__ adj4, int n3, int T) {
    int r = blockIdx.y;
    int i = blockIdx.x * 256 + threadIdx.x;
    if (i >= n3) return;
    int node = tri[(size_t)r * n3 + i];
    int t = i; if (t >= 2 * T) t -= 2 * T; else if (t >= T) t -= T;
    int pos = atomicAdd(&cur4[r * NPAD + node], 1);
    adj4[(size_t)r * n3 + pos] = t;
}

// meanx[t] = (x[a]+x[b]+x[c])/3 as bf16 row (reads pre-converted bf16 x)
__global__ __launch_bounds__(256)
void k_meanx(const int* __restrict__ tri, const ushortT* __restrict__ xb,
             ushortT* __restrict__ mx, int T) {
    int t = blockIdx.x * 4 + (threadIdx.x >> 6);
    if (t >= T) return;
    int lane = threadIdx.x & 63;
    int a = tri[t], b = tri[T + t], c = tri[2 * T + t];
    ushort4v va = *(const ushort4v*)(xb + (size_t)a * DIM + lane * 4);
    ushort4v vb = *(const ushort4v*)(xb + (size_t)b * DIM + lane * 4);
    ushort4v vc = *(const ushort4v*)(xb + (size_t)c * DIM + lane * 4);
    ushort4v o;
    o.x = f2bf((bf2f(va.x) + bf2f(vb.x) + bf2f(vc.x)) * (1.0f / 3.0f));
    o.y = f2bf((bf2f(va.y) + bf2f(vb.y) + bf2f(vc.y)) * (1.0f / 3.0f));
    o.z = f2bf((bf2f(va.z) + bf2f(vb.z) + bf2f(vc.z)) * (1.0f / 3.0f));
    o.w = f2bf((bf2f(va.w) + bf2f(vb.w) + bf2f(vc.w)) * (1.0f / 3.0f));
    *(ushort4v*)(mx + (size_t)t * DIM + lane * 4) = o;
}

// acc_bf[n] = (sum over incident triangles of meanx[t]) / max(cnt,1)
__global__ __launch_bounds__(256)
void k_gather(const int* __restrict__ ptr, const int* __restrict__ cnt,
              const int* __restrict__ adj, const ushortT* __restrict__ mx,
              ushortT* __restrict__ accb, int n) {
    int node = blockIdx.x * 4 + (threadIdx.x >> 6);
    if (node >= n) return;
    int lane = threadIdx.x & 63;
    int st = ptr[node], c = cnt[node];
    float a0 = 0.f, a1 = 0.f, a2 = 0.f, a3 = 0.f;
    for (int j = 0; j < c; ++j) {
        int t = adj[st + j];
        ushort4v v = *(const ushort4v*)(mx + (size_t)t * DIM + lane * 4);
        a0 += bf2f(v.x); a1 += bf2f(v.y); a2 += bf2f(v.z); a3 += bf2f(v.w);
    }
    float inv = 1.0f / fmaxf((float)c, 1.0f);
    ushort4v o; o.x = f2bf(a0 * inv); o.y = f2bf(a1 * inv);
    o.z = f2bf(a2 * inv); o.w = f2bf(a3 * inv);
    *(ushort4v*)(accb + (size_t)node * DIM + lane * 4) = o;
}

// -------------------------------- GEMM -------------------------------------
// C[m, col] = sum_k A[m,k] * W[col,k]. 128x128 tile, BK=32, 4 waves (2x2),
// each wave 64x64 via 4x4 MFMA 16x16x32 bf16. blockIdx.z batches relations.
// K-loop: depth-2 prefetch via 3-buffer LDS ring, counted vmcnt(4).
// Epilogue: TWO 64-row passes through a 64x133 f32 LDS tile (fits in the
// 48KB ring union -> LDS stays 49152 B -> 3 blocks/CU). Vectorized 16B
// stores + coalesced aux reads per pass.

#define BK 32
#define PADW 133                // 5r mod 32 spreads 64 rows -> 2-way max

__device__ __forceinline__ void async_cp16(char* lds, const char* glb) {
    __builtin_amdgcn_global_load_lds((const __attribute__((address_space(1))) unsigned int*)glb,
                                     (__attribute__((address_space(3))) unsigned int*)lds,
                                     16, 0, 0);
}

enum { M_BF16 = 0, M_ELU = 1, M_GATE = 2, M_QKV = 3, M_RES = 4, M_GELU = 5 };

template <int MODE>
__global__ __launch_bounds__(256)
void gemm_bt(const ushortT* __restrict__ A, int lda, size_t aStrZ,
             const ushortT* __restrict__ W, int ldw, size_t wStrZ,
             int M, int K,
             ushortT* __restrict__ outB, int ldo, size_t oStrZ,
             const float* __restrict__ bias,
             const ushortT* __restrict__ aux1,    // GATE: Gx (z-shared)
             const ushortT* __restrict__ aux2,    // GATE: xres (z-shared)
             int auxLd,
             const ushortT* __restrict__ resB,    // RES: residual row (bf16)
             size_t resStrZ) {
    const size_t zi = blockIdx.z;
    A += zi * aStrZ; W += zi * wStrZ;
    if (outB) outB += zi * oStrZ;
    if (resB) resB += zi * resStrZ;

    // union: K-loop ring (A 3x8KB @0, B 3x8KB @24576) | epilogue 64x133 f32
    __shared__ __align__(16) char smem[49152];
    const int tid  = threadIdx.x;
    const int wave = tid >> 6, lane = tid & 63;
    const int m0 = blockIdx.y * 128;
    const int n0 = blockIdx.x * 128;
    const int wm = (wave >> 1) * 64, wn = (wave & 1) * 64;

    floatx4 acc[4][4];
    #pragma unroll
    for (int i = 0; i < 4; ++i)
        #pragma unroll
        for (int j = 0; j < 4; ++j) acc[i][j] = (floatx4){0.f, 0.f, 0.f, 0.f};

    const int r4  = tid >> 2;            // row within 64-row chunk
    const int b16 = (tid & 3) * 16;      // byte offset in 64B row slice
    const char* Ab = (const char*)A + ((size_t)(m0 + r4) * lda) * 2 + b16;
    const char* Wb = (const char*)W + ((size_t)(n0 + r4) * ldw) * 2 + b16;

    const int kq = (lane >> 4) * 8;
    const int ra = wm + (lane & 15);
    const int rb = wn + (lane & 15);

    auto stage = [&](int buf, int k0) {
        char* Asl = smem + buf * 8192 + wave * 1024;          // wave-uniform base
        char* Bsl = smem + 24576 + buf * 8192 + wave * 1024;
        async_cp16(Asl,        Ab + k0 * 2);
        async_cp16(Asl + 4096, Ab + k0 * 2 + (size_t)64 * lda * 2);
        async_cp16(Bsl,        Wb + k0 * 2);
        async_cp16(Bsl + 4096, Wb + k0 * 2 + (size_t)64 * ldw * 2);
    };
    auto compute = [&](int buf) {
        const ushortT* Abuf = (const ushortT*)(smem + buf * 8192);
        const ushortT* Bbuf = (const ushortT*)(smem + 24576 + buf * 8192);
        short8 af[4], bfr[4];
        #pragma unroll
        for (int i = 0; i < 4; ++i) {
            af[i]  = *(const short8*)(Abuf + (ra + i * 16) * BK + kq);
            bfr[i] = *(const short8*)(Bbuf + (rb + i * 16) * BK + kq);
        }
        #pragma unroll
        for (int mi = 0; mi < 4; ++mi)
            #pragma unroll
            for (int ni = 0; ni < 4; ++ni)
                acc[mi][ni] = __builtin_amdgcn_mfma_f32_16x16x32_bf16(af[mi], bfr[ni], acc[mi][ni], 0, 0, 0);
    };

    const int NIT = K / BK;              // 8 or 16
    stage(0, 0);
    stage(1, BK);                        // 8 loads in flight
    asm volatile("s_waitcnt vmcnt(4)" ::: "memory");   // stage0 done
    __builtin_amdgcn_s_barrier();

    int bufc = 0, bufs = 2;
    for (int it = 0; it < NIT; ++it) {
        if (it + 2 < NIT) stage(bufs, (it + 2) * BK);   // keep 2 stages in flight
        compute(bufc);
        if (it + 1 < NIT) {
            if (it + 2 < NIT) asm volatile("s_waitcnt vmcnt(4)" ::: "memory");
            else              asm volatile("s_waitcnt vmcnt(0)" ::: "memory");
            __builtin_amdgcn_s_barrier();
        }
        bufc = (bufc == 2) ? 0 : bufc + 1;
        bufs = (bufs == 2) ? 0 : bufs + 1;
    }

    // ---- epilogue: two 64-row passes through f32 LDS -> vectorized stores ----
    __syncthreads();                     // all waves done with ring buffers
    float* Ct = (float*)smem;
    const int cl = lane & 15, rw = (lane >> 4) * 4;
    const int lr = tid >> 2;             // local row 0..63
    const int cb = (tid & 3) * 32;       // col quarter
    #pragma unroll
    for (int p = 0; p < 2; ++p) {
        if (wm == p * 64) {              // waves owning these 64 rows write
            #pragma unroll
            for (int mi = 0; mi < 4; ++mi)
                #pragma unroll
                for (int ni = 0; ni < 4; ++ni)
                    #pragma unroll
                    for (int e = 0; e < 4; ++e)
                        Ct[(mi * 16 + rw + e) * PADW + (wn + ni * 16 + cl)] = acc[mi][ni][e];
        }
        __syncthreads();
        const int m = m0 + p * 64 + lr;
        if (m < M) {
            #pragma unroll
            for (int k8 = 0; k8 < 4; ++k8) {
                const int c0  = cb + k8 * 8;
                const int col = n0 + c0;     // global col, multiple of 8
                float v[8];
                #pragma unroll
                for (int j = 0; j < 8; ++j) v[j] = Ct[lr * PADW + c0 + j];
                short8 ov;
                if (MODE == M_BF16) {
                    #pragma unroll
                    for (int j = 0; j < 8; ++j) ov[j] = (short)f2bf(v[j]);
                } else if (MODE == M_ELU) {
                    #pragma unroll
                    for (int j = 0; j < 8; ++j) {
                        float c = v[j] > 0.f ? v[j] : (__expf(v[j]) - 1.0f);
                        ov[j] = (short)f2bf(c);
                    }
                } else if (MODE == M_GATE) {
                    short8 gv = *(const short8*)(aux1 + (size_t)m * auxLd + col);
                    short8 xv = *(const short8*)(aux2 + (size_t)m * auxLd + col);
                    short8 uv = *(const short8*)(A + (size_t)m * lda + col);
                    #pragma unroll
                    for (int j = 0; j < 8; ++j) {
                        float g  = bf2f((ushortT)gv[j]);
                        float xr = bf2f((ushortT)xv[j]);
                        float u  = bf2f((ushortT)uv[j]);
                        float a  = 1.0f / (1.0f + __expf(-(v[j] + g + bias[col + j])));
                        float th = 1.0f - 2.0f / (__expf(2.0f * u) + 1.0f);
                        ov[j] = (short)f2bf(th * a + xr * (1.0f - a));
                    }
                } else if (MODE == M_QKV) {
                    #pragma unroll
                    for (int j = 0; j < 8; ++j) ov[j] = (short)f2bf(v[j] + bias[col + j]);
                } else if (MODE == M_RES) {
                    short8 rv = *(const short8*)(resB + (size_t)m * 256 + col);
                    #pragma unroll
                    for (int j = 0; j < 8; ++j)
                        ov[j] = (short)f2bf(v[j] + bias[col + j] + bf2f((ushortT)rv[j]));
                } else if (MODE == M_GELU) {
                    #pragma unroll
                    for (int j = 0; j < 8; ++j) {
                        float t = v[j] + bias[col + j];
                        ov[j] = (short)f2bf(0.5f * t * (1.0f + erf_as(t * 0.70710678118f)));
                    }
                }
                *(short8*)(&outB[(size_t)m * ldo + col]) = ov;
            }
        }
        if (p == 0) __syncthreads();     // readers done before pass-1 overwrite
    }
}

// ------------------------------ attention ----------------------------------
__global__ __launch_bounds__(256)
void attn_score(const ushortT* __restrict__ qk, size_t rstride,
                float* __restrict__ Aw, int nvalid) {
    int n = blockIdx.x * 4 + (threadIdx.x >> 6);
    if (n >= nvalid) return;
    int lane = threadIdx.x & 63;
    int head = lane >> 5, hl = lane & 31;
    int d = head * 128 + hl * 4;
    float q[NREL][4], k[NREL][4];
    #pragma unroll
    for (int r = 0; r < NREL; ++r) {
        const ushortT* base = qk + r * rstride + (size_t)n * 512;
        ushort4v qv = *(const ushort4v*)(base + d);
        ushort4v kv = *(const ushort4v*)(base + 256 + d);
        q[r][0] = bf2f(qv.x); q[r][1] = bf2f(qv.y); q[r][2] = bf2f(qv.z); q[r][3] = bf2f(qv.w);
        k[r][0] = bf2f(kv.x); k[r][1] = bf2f(kv.y); k[r][2] = bf2f(kv.z); k[r][3] = bf2f(kv.w);
    }
    float s[NREL][NREL];
    #pragma unroll
    for (int qr = 0; qr < NREL; ++qr)
        #pragma unroll
        for (int kr = 0; kr < NREL; ++kr) {
            float p = q[qr][0] * k[kr][0] + q[qr][1] * k[kr][1] +
                      q[qr][2] * k[kr][2] + q[qr][3] * k[kr][3];
            #pragma unroll
            for (int off = 1; off < 32; off <<= 1) p += __shfl_xor(p, off, 32);
            s[qr][kr] = p * 0.08838834764831845f;   // 1/sqrt(128)
        }
    if (hl < 16) {
        int qr = hl >> 2, kr = hl & 3;
        float mx = fmaxf(fmaxf(s[qr][0], s[qr][1]), fmaxf(s[qr][2], s[qr][3]));
        float e0 = __expf(s[qr][0] - mx), e1 = __expf(s[qr][1] - mx);
        float e2 = __expf(s[qr][2] - mx), e3 = __expf(s[qr][3] - mx);
        float e  = __expf(s[qr][kr] - mx);
        Aw[((size_t)n * 2 + head) * 16 + qr * 4 + kr] = e / (e0 + e1 + e2 + e3);
    }
}

// z[qr,n,:] = h[qr,n,:] + out_b + sum_kr (A0*vo_lo[kr] + A1*vo_hi[kr]);
// x1[qr] = LN1(z).  One wave per node, fully in-register + shfl reductions.
__global__ __launch_bounds__(256)
void attn_combine_ln1(const ushortT* __restrict__ vo4, size_t rstride,
                      const ushortT* __restrict__ h4, size_t hstride,
                      const float* __restrict__ Aw,
                      const float* __restrict__ ob,
                      const float* __restrict__ g, const float* __restrict__ b,
                      ushortT* __restrict__ x1, size_t x1str, int nvalid) {
    int n = blockIdx.x * 4 + (threadIdx.x >> 6);
    if (n >= nvalid) return;
    int lane = threadIdx.x & 63;
    int d4 = lane * 4;
    const float* ap = Aw + (size_t)n * 32;
    float a0[NREL][NREL], a1[NREL][NREL];
    #pragma unroll
    for (int qr = 0; qr < NREL; ++qr)
        #pragma unroll
        for (int kr = 0; kr < NREL; ++kr) {
            a0[qr][kr] = ap[qr * 4 + kr];
            a1[qr][kr] = ap[16 + qr * 4 + kr];
        }
    float vl[NREL][4], vh[NREL][4];
    #pragma unroll
    for (int kr = 0; kr < NREL; ++kr) {
        const ushortT* base = vo4 + kr * rstride + (size_t)n * 512;
        ushort4v lo = *(const ushort4v*)(base + d4);
        ushort4v hi = *(const ushort4v*)(base + 256 + d4);
        vl[kr][0] = bf2f(lo.x); vl[kr][1] = bf2f(lo.y); vl[kr][2] = bf2f(lo.z); vl[kr][3] = bf2f(lo.w);
        vh[kr][0] = bf2f(hi.x); vh[kr][1] = bf2f(hi.y); vh[kr][2] = bf2f(hi.z); vh[kr][3] = bf2f(hi.w);
    }
    float bb0 = ob[d4], bb1 = ob[d4 + 1], bb2 = ob[d4 + 2], bb3 = ob[d4 + 3];
    float g0 = g[d4], g1 = g[d4 + 1], g2 = g[d4 + 2], g3 = g[d4 + 3];
    float e0 = b[d4], e1 = b[d4 + 1], e2 = b[d4 + 2], e3 = b[d4 + 3];
    #pragma unroll
    for (int qr = 0; qr < NREL; ++qr) {
        ushort4v hv = *(const ushort4v*)(h4 + qr * hstride + (size_t)n * 256 + d4);
        float z0 = bf2f(hv.x) + bb0, z1 = bf2f(hv.y) + bb1;
        float z2 = bf2f(hv.z) + bb2, z3 = bf2f(hv.w) + bb3;
        #pragma unroll
        for (int kr = 0; kr < NREL; ++kr) {
            float c0 = a0[qr][kr], c1 = a1[qr][kr];
            z0 += c0 * vl[kr][0] + c1 * vh[kr][0];
            z1 += c0 * vl[kr][1] + c1 * vh[kr][1];
            z2 += c0 * vl[kr][2] + c1 * vh[kr][2];
            z3 += c0 * vl[kr][3] + c1 * vh[kr][3];
        }
        float s = z0 + z1 + z2 + z3;
        #pragma unroll
        for (int off = 1; off < 64; off <<= 1) s += __shfl_xor(s, off, 64);
        float mean = s * (1.0f / 256.0f);
        float dx = z0 - mean, dy = z1 - mean, dz = z2 - mean, dw = z3 - mean;
        float qs = dx * dx + dy * dy + dz * dz + dw * dw;
        #pragma unroll
        for (int off = 1; off < 64; off <<= 1) qs += __shfl_xor(qs, off, 64);
        float rstd = rsqrtf(qs * (1.0f / 256.0f) + 1e-5f);
        ushort4v o;
        o.x = f2bf(dx * rstd * g0 + e0); o.y = f2bf(dy * rstd * g1 + e1);
        o.z = f2bf(dz * rstd * g2 + e2); o.w = f2bf(dw * rstd * g3 + e3);
        *(ushort4v*)(x1 + qr * x1str + (size_t)n * 256 + d4) = o;
    }
}

// out[row] = 0.25 * sum_r LN2(zb[r][row]).  zb is bf16; written exactly once.
__global__ __launch_bounds__(256)
void ln2_out(const ushortT* __restrict__ zb, size_t zStrZ,
             const float* __restrict__ g, const float* __restrict__ b,
             float* __restrict__ outc, int n) {
    int row = blockIdx.x * 4 + (threadIdx.x >> 6);
    if (row >= n) return;
    int lane = threadIdx.x & 63, c0 = lane * 4;
    float g0 = g[c0], g1 = g[c0 + 1], g2 = g[c0 + 2], g3 = g[c0 + 3];
    float b0 = b[c0], b1 = b[c0 + 1], b2 = b[c0 + 2], b3 = b[c0 + 3];
    float o0 = 0.f, o1 = 0.f, o2 = 0.f, o3 = 0.f;
    #pragma unroll
    for (int r = 0; r < NREL; ++r) {
        ushort4v v = *(const ushort4v*)(zb + r * zStrZ + (size_t)row * 256 + c0);
        float vx = bf2f(v.x), vy = bf2f(v.y), vz = bf2f(v.z), vw = bf2f(v.w);
        float s = vx + vy + vz + vw;
        #pragma unroll
        for (int off = 1; off < 64; off <<= 1) s += __shfl_xor(s, off, 64);
        float mean = s * (1.0f / 256.0f);
        float dx = vx - mean, dy = vy - mean, dz = vz - mean, dw = vw - mean;
        float qs = dx * dx + dy * dy + dz * dz + dw * dw;
        #pragma unroll
        for (int off = 1; off < 64; off <<= 1) qs += __shfl_xor(qs, off, 64);
        float rstd = rsqrtf(qs * (1.0f / 256.0f) + 1e-5f);
        o0 += 0.25f * (dx * rstd * g0 + b0);
        o1 += 0.25f * (dy * rstd * g1 + b1);
        o2 += 0.25f * (dz * rstd * g2 + b2);
        o3 += 0.25f * (dw * rstd * g3 + b3);
    }
    float4 o; o.x = o0; o.y = o1; o.z = o2; o.w = o3;
    *(float4*)(outc + (size_t)row * 256 + c0) = o;
}

// ------------------------------ host ---------------------------------------

extern "C" void kernel_launch(void* const* d_in, const int* in_sizes, int n_in,
                              void* d_out, int out_size, void* d_ws, size_t ws_size,
                              hipStream_t stream) {
    const float* x      = (const float*)d_in[0];
    const int*   tri    = (const int*)d_in[1];
    const float* nodeW  = (const float*)d_in[3];
    const float* triW   = (const float*)d_in[4];
    const float* resW   = (const float*)d_in[5];
    const float* gateW  = (const float*)d_in[6];
    const float* gate_b = (const float*)d_in[7];
    const float* inW    = (const float*)d_in[8];
    const float* in_b   = (const float*)d_in[9];
    const float* outW   = (const float*)d_in[10];
    const float* out_b  = (const float*)d_in[11];
    const float* ln1g   = (const float*)d_in[12];
    const float* ln1b   = (const float*)d_in[13];
    const float* lin1W  = (const float*)d_in[14];
    const float* lin1b  = (const float*)d_in[15];
    const float* lin2W  = (const float*)d_in[16];
    const float* lin2b  = (const float*)d_in[17];
    const float* ln2g   = (const float*)d_in[18];
    const float* ln2b   = (const float*)d_in[19];
    float* out = (float*)d_out;

    // ---------------- persistent workspace ----------------
    char* ws = (char*)d_ws;
    size_t off = 0;
    auto alloc = [&](size_t bytes) -> char* {
        char* p = ws + off; off += (bytes + 255) & ~(size_t)255; return p;
    };
    ushortT* accAll  = (ushortT*)alloc((size_t)NREL * NPAD * 256 * 2);  // 205 MB
    ushortT* xall_b  = (ushortT*)alloc((size_t)NPAD * 256 * 2);         // 51 MB
    ushortT* wcomb   = (ushortT*)alloc((size_t)NREL * 65536 * 2);
    ushortT* xgW_b   = (ushortT*)alloc((size_t)131072 * 2);
    ushortT* gateW_b = (ushortT*)alloc((size_t)131072 * 2);
    ushortT* inW_b   = (ushortT*)alloc((size_t)131072 * 2);             // qk rows only
    ushortT* wvo_b   = (ushortT*)alloc((size_t)131072 * 2);
    ushortT* lin1_bf = (ushortT*)alloc((size_t)131072 * 2);
    ushortT* lin2_bf = (ushortT*)alloc((size_t)131072 * 2);
    float*   bvo     = (float*)  alloc((size_t)512 * 4);
    size_t persist = off;
    size_t scratch = (ws_size > persist) ? (ws_size - persist) : 0;
    char* S = ws + persist;

    // scatter-phase scratch (dead before chunk phase): batched CSR + meanx
    int*     cnt4  = (int*)(S);                            // 4*NPAD
    int*     ptr4  = cnt4 + 4 * NPAD;
    int*     cur4  = ptr4 + 4 * NPAD;
    int*     bsum4 = cur4 + 4 * NPAD;                      // 4*512
    int*     bpre4 = bsum4 + 4 * 512;
    int*     adj4  = bpre4 + 4 * 512;                      // 4*3*NTRI
    size_t csrBytes = ((char*)(adj4 + (size_t)4 * 3 * NTRI) - S + 255) & ~(size_t)255;
    const size_t mxBytes = (size_t)NTRI * 256 * 2;         // 77 MB
    if (scratch < csrBytes + mxBytes + 65536) return;
    ushortT* mxbf = (ushortT*)(S + csrBytes);

    // chunk scratch: 9344 B/row (phase-aliased layout, zb in bf16)
    const size_t ROWB = 9344;
    int TT = (NNODES + 127) / 128;              // 782
    int tpcMax = (int)(scratch / (ROWB * 128));
    if (tpcMax < 1) return;
    if (tpcMax > TT) tpcMax = TT;
    const int nchunks = (TT + tpcMax - 1) / tpcMax;
    const int tpc = (TT + nchunks - 1) / nchunks;       // balanced chunks
    const size_t NcPad = (size_t)tpc * 128;

    // chunk layout (byte-offset/row):
    //   A: xg@0 (1024) | ubf4@1024 (2048) | h4@3072 (2048)
    //   B: qk4@5120 (4096) | Aw@9216 (128) | vo4 alias qk4 | x1@0 (2048)
    //   C: ffg@2048 (4096) | zbb@6144 (2048, bf16)
    ushortT* xg   = (ushortT*)(S);
    ushortT* ubf4 = (ushortT*)(S + 1024 * NcPad);
    ushortT* h4   = (ushortT*)(S + 3072 * NcPad);
    ushortT* qk4  = (ushortT*)(S + 5120 * NcPad);
    ushortT* vo4  = qk4;
    ushortT* x1   = (ushortT*)(S);
    ushortT* ffg  = (ushortT*)(S + 2048 * NcPad);
    ushortT* zbb  = (ushortT*)(S + 6144 * NcPad);
    float*   Aw   = (float*)  (S + 9216 * NcPad);

    // ---------------- weights to bf16 + folds ----------------
    cvt_f32_bf16<<<2048, 256, 0, stream>>>(x, xall_b, NNODES * 64);
    cvt_f32_bf16<<<64, 256, 0, stream>>>(gateW, gateW_b, 131072 / 4);
    cvt_f32_bf16<<<64, 256, 0, stream>>>(inW,   inW_b,   131072 / 4);
    cvt_f32_bf16<<<64, 256, 0, stream>>>(lin1W, lin1_bf, 131072 / 4);
    cvt_f32_bf16<<<64, 256, 0, stream>>>(lin2W, lin2_bf, 131072 / 4);
    pack_xg<<<512, 256, 0, stream>>>(resW, gateW, xgW_b);
    pack_wvo<<<512, 256, 0, stream>>>(outW, inW, wvo_b);
    calc_bvo<<<2, 256, 0, stream>>>(outW, in_b, bvo);
    wcomb_kernel<<<1024, 256, 0, stream>>>(nodeW, triW, wcomb);

    // ---------------- scatter phase: batched CSR, per-relation gather ------
    const int NB = (NNODES + 255) / 256;        // 391 scan blocks
    const int N3B = (3 * NTRI + 255) / 256;
    (void)hipMemsetAsync(cnt4, 0, (size_t)4 * NPAD * 4, stream);
    k_count4<<<dim3(N3B, 4), 256, 0, stream>>>(tri, cnt4, 3 * NTRI);
    k_scan1<<<dim3(NB, 4), 256, 0, stream>>>(cnt4, ptr4, bsum4, NNODES);
    k_scan2<<<4, 64, 0, stream>>>(bsum4, bpre4, NB);
    k_scan3<<<dim3(NB, 4), 256, 0, stream>>>(bpre4, ptr4, cur4, NNODES);
    k_fill4<<<dim3(N3B, 4), 256, 0, stream>>>(tri, cur4, adj4, 3 * NTRI, NTRI);
    for (int r = 0; r < NREL; ++r) {
        const int* trir = tri + (size_t)r * 3 * NTRI;
        k_meanx<<<(NTRI + 3) / 4, 256, 0, stream>>>(trir, xall_b, mxbf, NTRI);
        k_gather<<<(NNODES + 3) / 4, 256, 0, stream>>>(
            ptr4 + (size_t)r * NPAD, cnt4 + (size_t)r * NPAD,
            adj4 + (size_t)r * 3 * NTRI, mxbf,
            accAll + (size_t)r * NPAD * 256, NNODES);
    }

    // ---------------- chunked main pipeline ----------------
    for (int ci = 0; ci < nchunks; ++ci) {
        const int rows0 = ci * tpc * 128;
        int mact = NNODES - rows0;
        if (mact <= 0) break;
        if (mact > tpc * 128) mact = tpc * 128;
        const int tiles = (mact + 127) / 128;
        const dim3 g2z(2, tiles, NREL), g4z(4, tiles, NREL);
        const int nwblk = (mact + 3) / 4;
        float* outc = out + (size_t)rows0 * 256;
        const ushortT* xbf = xall_b + (size_t)rows0 * 256;

        // xg = [x@res_W.T | x@gate_W[:, :D].T]  (N=512, packed weight)
        gemm_bt<M_BF16><<<dim3(4, tiles), 256, 0, stream>>>(xbf, 256, 0, xgW_b, 256, 0, mact, 256,
            xg, 512, 0, nullptr, nullptr, nullptr, 0, nullptr, 0);
        // u[r] = elu(acc[r] @ W_comb[r].T)
        gemm_bt<M_ELU><<<g2z, 256, 0, stream>>>(
            accAll + (size_t)rows0 * 256, 256, (size_t)NPAD * 256,
            wcomb, 256, 65536, mact, 256,
            ubf4, 256, 256 * NcPad, nullptr, nullptr, nullptr, 0, nullptr, 0);
        // a = sigmoid(u@gW2.T + Gx + b); h = tanh(u)*a + xres*(1-a)
        gemm_bt<M_GATE><<<g2z, 256, 0, stream>>>(
            ubf4, 256, 256 * NcPad, gateW_b + 256, 512, 0, mact, 256,
            h4, 256, 256 * NcPad, gate_b, xg + 256, xg, 512, nullptr, 0);
        // qk[r] = h[r] @ in_W[0:512].T + b
        gemm_bt<M_QKV><<<g4z, 256, 0, stream>>>(
            h4, 256, 256 * NcPad, inW_b, 256, 0, mact, 256,
            qk4, 512, 512 * NcPad, in_b, nullptr, nullptr, 0, nullptr, 0);
        attn_score<<<nwblk, 256, 0, stream>>>(qk4, 512 * NcPad, Aw, mact);
        // vo[r] = h[r] @ Wvo.T + bvo   (out_W folded; qk region dead)
        gemm_bt<M_QKV><<<g4z, 256, 0, stream>>>(
            h4, 256, 256 * NcPad, wvo_b, 256, 0, mact, 256,
            vo4, 512, 512 * NcPad, bvo, nullptr, nullptr, 0, nullptr, 0);
        // z = h + combine(A, vo) + out_b ; x1 = LN1(z)   (fused, in-register)
        attn_combine_ln1<<<nwblk, 256, 0, stream>>>(vo4, 512 * NcPad, h4, 256 * NcPad,
            Aw, out_b, ln1g, ln1b, x1, 256 * NcPad, mact);
        // ffg = gelu(x1 @ lin1_W.T + b)
        gemm_bt<M_GELU><<<g4z, 256, 0, stream>>>(x1, 256, 256 * NcPad, lin1_bf, 256, 0, mact, 256,
            ffg, 512, 512 * NcPad, lin1b, nullptr, nullptr, 0, nullptr, 0);
        // z = x1 + ffg @ lin2_W.T + b   (bf16 out)
        gemm_bt<M_RES><<<g2z, 256, 0, stream>>>(ffg, 512, 512 * NcPad, lin2_bf, 512, 0, mact, 512,
            zbb, 256, 256 * NcPad, lin2b, nullptr, nullptr, 0, x1, 256 * NcPad);
        // out = 0.25 * sum_r LN2(z[r])
        ln2_out<<<nwblk, 256, 0, stream>>>(zbb, 256 * NcPad, ln2g, ln2b, outc, mact);
    }
}

// Round 15
// 3028.008 us; speedup vs baseline: 1.1171x; 1.0604x over previous
//
#include <hip/hip_runtime.h>

// ---------------------------------------------------------------------------
// HeteroSimplexLayer on MI355X (gfx950).
// v8: = v7 + XCD-partitioned CSR count/fill: 8 node-partitions, blockIdx&7
// selects partition (~XCD under round-robin dispatch) so all writes to an
// adj/cnt cache line come from one XCD -> line fills in its L2, writes back
// once (v7: 103 MB written for 7.2 MB of adj = cross-XCD line migration).
// GEMM (depth-2 ring + 2-pass vectorized epilogue) unchanged from v7.
// ---------------------------------------------------------------------------

#define NNODES 100000
#define NPAD   100096          // 782 tiles of 128
#define DIM    256
#define NREL   4
#define NTRI   150000
#define NPART  8
#define PSIZE  (NPAD / NPART)  // 12512

typedef unsigned short ushortT;
typedef __attribute__((ext_vector_type(8)))  short   short8;
typedef __attribute__((ext_vector_type(4)))  float   floatx4;
typedef __attribute__((ext_vector_type(4)))  unsigned short ushort4v;

__device__ __forceinline__ float bf2f(ushortT u) {
    union { unsigned int i; float f; } c; c.i = ((unsigned int)u) << 16; return c.f;
}
__device__ __forceinline__ ushortT f2bf(float f) {
    union { float f; unsigned int i; } c; c.f = f;
    unsigned int x = c.i;
    x += 0x7fffu + ((x >> 16) & 1u);      // RNE
    return (ushortT)(x >> 16);
}
// Abramowitz-Stegun 7.1.26, |err| < 1.5e-7 (exact at bf16 output precision)
__device__ __forceinline__ float erf_as(float x) {
    float ax = fabsf(x);
    float k  = 1.0f / (1.0f + 0.3275911f * ax);
    float p  = k * (0.254829592f + k * (-0.284496736f + k * (1.421413741f +
               k * (-1.453152027f + k * 1.061405429f))));
    float r  = 1.0f - p * __expf(-ax * ax);
    return copysignf(r, x);
}

// -------------------------------- small kernels ----------------------------

__global__ void cvt_f32_bf16(const float* __restrict__ in, ushortT* __restrict__ out, int n4) {
    int i = blockIdx.x * blockDim.x + threadIdx.x;
    int stride = gridDim.x * blockDim.x;
    for (; i < n4; i += stride) {
        float4 v = ((const float4*)in)[i];
        ushort4v o; o.x = f2bf(v.x); o.y = f2bf(v.y); o.z = f2bf(v.z); o.w = f2bf(v.w);
        ((ushort4v*)out)[i] = o;
    }
}

// W_comb[r][o][k] = sum_j tri_W[r][o][j] * node_W[r][j][k]
__global__ void wcomb_kernel(const float* __restrict__ nodeW, const float* __restrict__ triW,
                             ushortT* __restrict__ wcomb) {
    int idx = blockIdx.x * 256 + threadIdx.x;       // r*65536 + o*256 + k
    int r = idx >> 16, o = (idx >> 8) & 255, k = idx & 255;
    const float* tw = triW  + ((size_t)r << 16) + o * 256;
    const float* nw = nodeW + ((size_t)r << 16) + k;
    float s = 0.f;
    #pragma unroll 8
    for (int j = 0; j < 256; ++j) s += tw[j] * nw[(size_t)j * 256];
    wcomb[idx] = f2bf(s);
}

// xgW[512][256]: rows 0..255 = res_W rows; rows 256..511 = gate_W[:, :256] rows
__global__ void pack_xg(const float* __restrict__ resW, const float* __restrict__ gateW,
                        ushortT* __restrict__ o) {
    int idx = blockIdx.x * 256 + threadIdx.x;       // 512*256
    int r = idx >> 8, k = idx & 255;
    float v = (r < 256) ? resW[r * 256 + k] : gateW[(size_t)(r - 256) * 512 + k];
    o[idx] = f2bf(v);
}

// Wvo[512][256]: rows 0..255 = outW[:, :128] @ inW[512:640]; rows 256..511 hi half
__global__ void pack_wvo(const float* __restrict__ outW, const float* __restrict__ inW,
                         ushortT* __restrict__ o) {
    int idx = blockIdx.x * 256 + threadIdx.x;       // 512*256
    int r = idx >> 8, k = idx & 255;
    int orow = r & 255, d0 = (r >> 8) * 128;
    float s = 0.f;
    #pragma unroll 8
    for (int j = 0; j < 128; ++j)
        s += outW[orow * 256 + d0 + j] * inW[(size_t)(512 + d0 + j) * 256 + k];
    o[idx] = f2bf(s);
}

// bvo[c] = per-half fold of in_b[512:768] through outW (out_b added in combine)
__global__ void calc_bvo(const float* __restrict__ outW, const float* __restrict__ in_b,
                         float* __restrict__ bvo) {
    int c = blockIdx.x * 256 + threadIdx.x;         // 512
    int orow = c & 255, d0 = (c >> 8) * 128;
    float s = 0.f;
    #pragma unroll 8
    for (int j = 0; j < 128; ++j) s += outW[orow * 256 + d0 + j] * in_b[512 + d0 + j];
    bvo[c] = s;
}

// ---------------- CSR build, batched over relations, XCD-partitioned -------
// part = blockIdx.x & 7 owns nodes [part*PSIZE, (part+1)*PSIZE). Under
// round-robin dispatch consecutive blocks land on distinct XCDs, so all
// writes to a given cnt/adj line come from one XCD (no line migration).

__global__ void k_count8(const int* __restrict__ tri, int* __restrict__ cnt4, int n3) {
    int r = blockIdx.y;
    int part = blockIdx.x & 7;
    int i = (blockIdx.x >> 3) * 256 + threadIdx.x;
    if (i >= n3) return;
    int node = tri[(size_t)r * n3 + i];
    if (node / PSIZE != part) return;
    atomicAdd(&cnt4[r * NPAD + node], 1);
}

__global__ void k_scan1(const int* __restrict__ cnt4, int* __restrict__ ptr4,
                        int* __restrict__ bsum4, int n) {
    int r = blockIdx.y;
    const int* cnt = cnt4 + r * NPAD;
    int* ptr = ptr4 + r * NPAD;
    int* bsum = bsum4 + r * 512;
    __shared__ int s[256];
    int i = blockIdx.x * 256 + threadIdx.x;
    int v = (i < n) ? cnt[i] : 0;
    s[threadIdx.x] = v; __syncthreads();
    for (int off = 1; off < 256; off <<= 1) {
        int t = (threadIdx.x >= off) ? s[threadIdx.x - off] : 0;
        __syncthreads();
        s[threadIdx.x] += t;
        __syncthreads();
    }
    if (i < n) ptr[i] = s[threadIdx.x] - v;            // block-local exclusive
    if (threadIdx.x == 255) bsum[blockIdx.x] = s[255];
}

__global__ void k_scan2(const int* __restrict__ bsum4, int* __restrict__ bpre4, int nb) {
    int r = blockIdx.x;
    const int* bsum = bsum4 + r * 512;
    int* bpre = bpre4 + r * 512;
    int lane = threadIdx.x & 63;
    int run = 0;
    for (int c = 0; c < nb; c += 64) {
        int idx = c + lane;
        int v = (idx < nb) ? bsum[idx] : 0;
        int incl = v;
        #pragma unroll
        for (int off = 1; off < 64; off <<= 1) {
            int t = __shfl_up(incl, off, 64);
            if (lane >= off) incl += t;
        }
        if (idx < nb) bpre[idx] = run + incl - v;
        run += __shfl(incl, 63, 64);
    }
}

__global__ void k_scan3(const int* __restrict__ bpre4, int* __restrict__ ptr4,
                        int* __restrict__ cur4, int n) {
    int r = blockIdx.y;
    int i = blockIdx.x * 256 + threadIdx.x;
    if (i < n) {
        int p = ptr4[r * NPAD + i] + bpre4[r * 512 + blockIdx.x];
        ptr4[r * NPAD + i] = p; cur4[r * NPAD + i] = p;
    }
}

__global__ void k_fill8(const int* __restrict__ tri, int* __restrict__ cur4,
                        int* __restrict__ adj4, int n3, int T) {
    int r = blockIdx.y;
    int part = blockIdx.x & 7;
    int i = (blockIdx.x >> 3) * 256 + threadIdx.x;
    if (i >= n3) return;
    int node = tri[(size_t)r * n3 + i];
    if (node / PSIZE != part) return;
    int t = i; if (t >= 2 * T) t -= 2 * T; else if (t >= T) t -= T;
    int pos = atomicAdd(&cur4[r * NPAD + node], 1);
    adj4[(size_t)r * n3 + pos] = t;
}

// meanx[t] = (x[a]+x[b]+x[c])/3 as bf16 row (reads pre-converted bf16 x)
__global__ __launch_bounds__(256)
void k_meanx(const int* __restrict__ tri, const ushortT* __restrict__ xb,
             ushortT* __restrict__ mx, int T) {
    int t = blockIdx.x * 4 + (threadIdx.x >> 6);
    if (t >= T) return;
    int lane = threadIdx.x & 63;
    int a = tri[t], b = tri[T + t], c = tri[2 * T + t];
    ushort4v va = *(const ushort4v*)(xb + (size_t)a * DIM + lane * 4);
    ushort4v vb = *(const ushort4v*)(xb + (size_t)b * DIM + lane * 4);
    ushort4v vc = *(const ushort4v*)(xb + (size_t)c * DIM + lane * 4);
    ushort4v o;
    o.x = f2bf((bf2f(va.x) + bf2f(vb.x) + bf2f(vc.x)) * (1.0f / 3.0f));
    o.y = f2bf((bf2f(va.y) + bf2f(vb.y) + bf2f(vc.y)) * (1.0f / 3.0f));
    o.z = f2bf((bf2f(va.z) + bf2f(vb.z) + bf2f(vc.z)) * (1.0f / 3.0f));
    o.w = f2bf((bf2f(va.w) + bf2f(vb.w) + bf2f(vc.w)) * (1.0f / 3.0f));
    *(ushort4v*)(mx + (size_t)t * DIM + lane * 4) = o;
}

// acc_bf[n] = (sum over incident triangles of meanx[t]) / max(cnt,1)
__global__ __launch_bounds__(256)
void k_gather(const int* __restrict__ ptr, const int* __restrict__ cnt,
              const int* __restrict__ adj, const ushortT* __restrict__ mx,
              ushortT* __restrict__ accb, int n) {
    int node = blockIdx.x * 4 + (threadIdx.x >> 6);
    if (node >= n) return;
    int lane = threadIdx.x & 63;
    int st = ptr[node], c = cnt[node];
    float a0 = 0.f, a1 = 0.f, a2 = 0.f, a3 = 0.f;
    for (int j = 0; j < c; ++j) {
        int t = adj[st + j];
        ushort4v v = *(const ushort4v*)(mx + (size_t)t * DIM + lane * 4);
        a0 += bf2f(v.x); a1 += bf2f(v.y); a2 += bf2f(v.z); a3 += bf2f(v.w);
    }
    float inv = 1.0f / fmaxf((float)c, 1.0f);
    ushort4v o; o.x = f2bf(a0 * inv); o.y = f2bf(a1 * inv);
    o.z = f2bf(a2 * inv); o.w = f2bf(a3 * inv);
    *(ushort4v*)(accb + (size_t)node * DIM + lane * 4) = o;
}

// -------------------------------- GEMM -------------------------------------
// C[m, col] = sum_k A[m,k] * W[col,k]. 128x128 tile, BK=32, 4 waves (2x2),
// each wave 64x64 via 4x4 MFMA 16x16x32 bf16. blockIdx.z batches relations.
// K-loop: depth-2 prefetch via 3-buffer LDS ring, counted vmcnt(4).
// Epilogue: TWO 64-row passes through a 64x133 f32 LDS tile (fits in the
// 48KB ring union -> LDS stays 49152 B -> 3 blocks/CU).

#define BK 32
#define PADW 133                // 5r mod 32 spreads rows across banks

__device__ __forceinline__ void async_cp16(char* lds, const char* glb) {
    __builtin_amdgcn_global_load_lds((const __attribute__((address_space(1))) unsigned int*)glb,
                                     (__attribute__((address_space(3))) unsigned int*)lds,
                                     16, 0, 0);
}

enum { M_BF16 = 0, M_ELU = 1, M_GATE = 2, M_QKV = 3, M_RES = 4, M_GELU = 5 };

template <int MODE>
__global__ __launch_bounds__(256)
void gemm_bt(const ushortT* __restrict__ A, int lda, size_t aStrZ,
             const ushortT* __restrict__ W, int ldw, size_t wStrZ,
             int M, int K,
             ushortT* __restrict__ outB, int ldo, size_t oStrZ,
             const float* __restrict__ bias,
             const ushortT* __restrict__ aux1,    // GATE: Gx (z-shared)
             const ushortT* __restrict__ aux2,    // GATE: xres (z-shared)
             int auxLd,
             const ushortT* __restrict__ resB,    // RES: residual row (bf16)
             size_t resStrZ) {
    const size_t zi = blockIdx.z;
    A += zi * aStrZ; W += zi * wStrZ;
    if (outB) outB += zi * oStrZ;
    if (resB) resB += zi * resStrZ;

    // union: K-loop ring (A 3x8KB @0, B 3x8KB @24576) | epilogue 64x133 f32
    __shared__ __align__(16) char smem[49152];
    const int tid  = threadIdx.x;
    const int wave = tid >> 6, lane = tid & 63;
    const int m0 = blockIdx.y * 128;
    const int n0 = blockIdx.x * 128;
    const int wm = (wave >> 1) * 64, wn = (wave & 1) * 64;

    floatx4 acc[4][4];
    #pragma unroll
    for (int i = 0; i < 4; ++i)
        #pragma unroll
        for (int j = 0; j < 4; ++j) acc[i][j] = (floatx4){0.f, 0.f, 0.f, 0.f};

    const int r4  = tid >> 2;            // row within 64-row chunk
    const int b16 = (tid & 3) * 16;      // byte offset in 64B row slice
    const char* Ab = (const char*)A + ((size_t)(m0 + r4) * lda) * 2 + b16;
    const char* Wb = (const char*)W + ((size_t)(n0 + r4) * ldw) * 2 + b16;

    const int kq = (lane >> 4) * 8;
    const int ra = wm + (lane & 15);
    const int rb = wn + (lane & 15);

    auto stage = [&](int buf, int k0) {
        char* Asl = smem + buf * 8192 + wave * 1024;          // wave-uniform base
        char* Bsl = smem + 24576 + buf * 8192 + wave * 1024;
        async_cp16(Asl,        Ab + k0 * 2);
        async_cp16(Asl + 4096, Ab + k0 * 2 + (size_t)64 * lda * 2);
        async_cp16(Bsl,        Wb + k0 * 2);
        async_cp16(Bsl + 4096, Wb + k0 * 2 + (size_t)64 * ldw * 2);
    };
    auto compute = [&](int buf) {
        const ushortT* Abuf = (const ushortT*)(smem + buf * 8192);
        const ushortT* Bbuf = (const ushortT*)(smem + 24576 + buf * 8192);
        short8 af[4], bfr[4];
        #pragma unroll
        for (int i = 0; i < 4; ++i) {
            af[i]  = *(const short8*)(Abuf + (ra + i * 16) * BK + kq);
            bfr[i] = *(const short8*)(Bbuf + (rb + i * 16) * BK + kq);
        }
        #pragma unroll
        for (int mi = 0; mi < 4; ++mi)
            #pragma unroll
            for (int ni = 0; ni < 4; ++ni)
                acc[mi][ni] = __builtin_amdgcn_mfma_f32_16x16x32_bf16(af[mi], bfr[ni], acc[mi][ni], 0, 0, 0);
    };

    const int NIT = K / BK;              // 8 or 16
    stage(0, 0);
    stage(1, BK);                        // 8 loads in flight
    asm volatile("s_waitcnt vmcnt(4)" ::: "memory");   // stage0 done
    __builtin_amdgcn_s_barrier();

    int bufc = 0, bufs = 2;
    for (int it = 0; it < NIT; ++it) {
        if (it + 2 < NIT) stage(bufs, (it + 2) * BK);   // keep 2 stages in flight
        compute(bufc);
        if (it + 1 < NIT) {
            if (it + 2 < NIT) asm volatile("s_waitcnt vmcnt(4)" ::: "memory");
            else              asm volatile("s_waitcnt vmcnt(0)" ::: "memory");
            __builtin_amdgcn_s_barrier();
        }
        bufc = (bufc == 2) ? 0 : bufc + 1;
        bufs = (bufs == 2) ? 0 : bufs + 1;
    }

    // ---- epilogue: two 64-row passes through f32 LDS -> vectorized stores ----
    __syncthreads();                     // all waves done with ring buffers
    float* Ct = (float*)smem;
    const int cl = lane & 15, rw = (lane >> 4) * 4;
    const int lr = tid >> 2;             // local row 0..63
    const int cb = (tid & 3) * 32;       // col quarter
    #pragma unroll
    for (int p = 0; p < 2; ++p) {
        if (wm == p * 64) {              // waves owning these 64 rows write
            #pragma unroll
            for (int mi = 0; mi < 4; ++mi)
                #pragma unroll
                for (int ni = 0; ni < 4; ++ni)
                    #pragma unroll
                    for (int e = 0; e < 4; ++e)
                        Ct[(mi * 16 + rw + e) * PADW + (wn + ni * 16 + cl)] = acc[mi][ni][e];
        }
        __syncthreads();
        const int m = m0 + p * 64 + lr;
        if (m < M) {
            #pragma unroll
            for (int k8 = 0; k8 < 4; ++k8) {
                const int c0  = cb + k8 * 8;
                const int col = n0 + c0;     // global col, multiple of 8
                float v[8];
                #pragma unroll
                for (int j = 0; j < 8; ++j) v[j] = Ct[lr * PADW + c0 + j];
                short8 ov;
                if (MODE == M_BF16) {
                    #pragma unroll
                    for (int j = 0; j < 8; ++j) ov[j] = (short)f2bf(v[j]);
                } else if (MODE == M_ELU) {
                    #pragma unroll
                    for (int j = 0; j < 8; ++j) {
                        float c = v[j] > 0.f ? v[j] : (__expf(v[j]) - 1.0f);
                        ov[j] = (short)f2bf(c);
                    }
                } else if (MODE == M_GATE) {
                    short8 gv = *(const short8*)(aux1 + (size_t)m * auxLd + col);
                    short8 xv = *(const short8*)(aux2 + (size_t)m * auxLd + col);
                    short8 uv = *(const short8*)(A + (size_t)m * lda + col);
                    #pragma unroll
                    for (int j = 0; j < 8; ++j) {
                        float g  = bf2f((ushortT)gv[j]);
                        float xr = bf2f((ushortT)xv[j]);
                        float u  = bf2f((ushortT)uv[j]);
                        float a  = 1.0f / (1.0f + __expf(-(v[j] + g + bias[col + j])));
                        float th = 1.0f - 2.0f / (__expf(2.0f * u) + 1.0f);
                        ov[j] = (short)f2bf(th * a + xr * (1.0f - a));
                    }
                } else if (MODE == M_QKV) {
                    #pragma unroll
                    for (int j = 0; j < 8; ++j) ov[j] = (short)f2bf(v[j] + bias[col + j]);
                } else if (MODE == M_RES) {
                    short8 rv = *(const short8*)(resB + (size_t)m * 256 + col);
                    #pragma unroll
                    for (int j = 0; j < 8; ++j)
                        ov[j] = (short)f2bf(v[j] + bias[col + j] + bf2f((ushortT)rv[j]));
                } else if (MODE == M_GELU) {
                    #pragma unroll
                    for (int j = 0; j < 8; ++j) {
                        float t = v[j] + bias[col + j];
                        ov[j] = (short)f2bf(0.5f * t * (1.0f + erf_as(t * 0.70710678118f)));
                    }
                }
                *(short8*)(&outB[(size_t)m * ldo + col]) = ov;
            }
        }
        if (p == 0) __syncthreads();     // readers done before pass-1 overwrite
    }
}

// ------------------------------ attention ----------------------------------
__global__ __launch_bounds__(256)
void attn_score(const ushortT* __restrict__ qk, size_t rstride,
                float* __restrict__ Aw, int nvalid) {
    int n = blockIdx.x * 4 + (threadIdx.x >> 6);
    if (n >= nvalid) return;
    int lane = threadIdx.x & 63;
    int head = lane >> 5, hl = lane & 31;
    int d = head * 128 + hl * 4;
    float q[NREL][4], k[NREL][4];
    #pragma unroll
    for (int r = 0; r < NREL; ++r) {
        const ushortT* base = qk + r * rstride + (size_t)n * 512;
        ushort4v qv = *(const ushort4v*)(base + d);
        ushort4v kv = *(const ushort4v*)(base + 256 + d);
        q[r][0] = bf2f(qv.x); q[r][1] = bf2f(qv.y); q[r][2] = bf2f(qv.z); q[r][3] = bf2f(qv.w);
        k[r][0] = bf2f(kv.x); k[r][1] = bf2f(kv.y); k[r][2] = bf2f(kv.z); k[r][3] = bf2f(kv.w);
    }
    float s[NREL][NREL];
    #pragma unroll
    for (int qr = 0; qr < NREL; ++qr)
        #pragma unroll
        for (int kr = 0; kr < NREL; ++kr) {
            float p = q[qr][0] * k[kr][0] + q[qr][1] * k[kr][1] +
                      q[qr][2] * k[kr][2] + q[qr][3] * k[kr][3];
            #pragma unroll
            for (int off = 1; off < 32; off <<= 1) p += __shfl_xor(p, off, 32);
            s[qr][kr] = p * 0.08838834764831845f;   // 1/sqrt(128)
        }
    if (hl < 16) {
        int qr = hl >> 2, kr = hl & 3;
        float mx = fmaxf(fmaxf(s[qr][0], s[qr][1]), fmaxf(s[qr][2], s[qr][3]));
        float e0 = __expf(s[qr][0] - mx), e1 = __expf(s[qr][1] - mx);
        float e2 = __expf(s[qr][2] - mx), e3 = __expf(s[qr][3] - mx);
        float e  = __expf(s[qr][kr] - mx);
        Aw[((size_t)n * 2 + head) * 16 + qr * 4 + kr] = e / (e0 + e1 + e2 + e3);
    }
}

// z[qr,n,:] = h[qr,n,:] + out_b + sum_kr (A0*vo_lo[kr] + A1*vo_hi[kr]);
// x1[qr] = LN1(z).  One wave per node, fully in-register + shfl reductions.
__global__ __launch_bounds__(256)
void attn_combine_ln1(const ushortT* __restrict__ vo4, size_t rstride,
                      const ushortT* __restrict__ h4, size_t hstride,
                      const float* __restrict__ Aw,
                      const float* __restrict__ ob,
                      const float* __restrict__ g, const float* __restrict__ b,
                      ushortT* __restrict__ x1, size_t x1str, int nvalid) {
    int n = blockIdx.x * 4 + (threadIdx.x >> 6);
    if (n >= nvalid) return;
    int lane = threadIdx.x & 63;
    int d4 = lane * 4;
    const float* ap = Aw + (size_t)n * 32;
    float a0[NREL][NREL], a1[NREL][NREL];
    #pragma unroll
    for (int qr = 0; qr < NREL; ++qr)
        #pragma unroll
        for (int kr = 0; kr < NREL; ++kr) {
            a0[qr][kr] = ap[qr * 4 + kr];
            a1[qr][kr] = ap[16 + qr * 4 + kr];
        }
    float vl[NREL][4], vh[NREL][4];
    #pragma unroll
    for (int kr = 0; kr < NREL; ++kr) {
        const ushortT* base = vo4 + kr * rstride + (size_t)n * 512;
        ushort4v lo = *(const ushort4v*)(base + d4);
        ushort4v hi = *(const ushort4v*)(base + 256 + d4);
        vl[kr][0] = bf2f(lo.x); vl[kr][1] = bf2f(lo.y); vl[kr][2] = bf2f(lo.z); vl[kr][3] = bf2f(lo.w);
        vh[kr][0] = bf2f(hi.x); vh[kr][1] = bf2f(hi.y); vh[kr][2] = bf2f(hi.z); vh[kr][3] = bf2f(hi.w);
    }
    float bb0 = ob[d4], bb1 = ob[d4 + 1], bb2 = ob[d4 + 2], bb3 = ob[d4 + 3];
    float g0 = g[d4], g1 = g[d4 + 1], g2 = g[d4 + 2], g3 = g[d4 + 3];
    float e0 = b[d4], e1 = b[d4 + 1], e2 = b[d4 + 2], e3 = b[d4 + 3];
    #pragma unroll
    for (int qr = 0; qr < NREL; ++qr) {
        ushort4v hv = *(const ushort4v*)(h4 + qr * hstride + (size_t)n * 256 + d4);
        float z0 = bf2f(hv.x) + bb0, z1 = bf2f(hv.y) + bb1;
        float z2 = bf2f(hv.z) + bb2, z3 = bf2f(hv.w) + bb3;
        #pragma unroll
        for (int kr = 0; kr < NREL; ++kr) {
            float c0 = a0[qr][kr], c1 = a1[qr][kr];
            z0 += c0 * vl[kr][0] + c1 * vh[kr][0];
            z1 += c0 * vl[kr][1] + c1 * vh[kr][1];
            z2 += c0 * vl[kr][2] + c1 * vh[kr][2];
            z3 += c0 * vl[kr][3] + c1 * vh[kr][3];
        }
        float s = z0 + z1 + z2 + z3;
        #pragma unroll
        for (int off = 1; off < 64; off <<= 1) s += __shfl_xor(s, off, 64);
        float mean = s * (1.0f / 256.0f);
        float dx = z0 - mean, dy = z1 - mean, dz = z2 - mean, dw = z3 - mean;
        float qs = dx * dx + dy * dy + dz * dz + dw * dw;
        #pragma unroll
        for (int off = 1; off < 64; off <<= 1) qs += __shfl_xor(qs, off, 64);
        float rstd = rsqrtf(qs * (1.0f / 256.0f) + 1e-5f);
        ushort4v o;
        o.x = f2bf(dx * rstd * g0 + e0); o.y = f2bf(dy * rstd * g1 + e1);
        o.z = f2bf(dz * rstd * g2 + e2); o.w = f2bf(dw * rstd * g3 + e3);
        *(ushort4v*)(x1 + qr * x1str + (size_t)n * 256 + d4) = o;
    }
}

// out[row] = 0.25 * sum_r LN2(zb[r][row]).  zb is bf16; written exactly once.
__global__ __launch_bounds__(256)
void ln2_out(const ushortT* __restrict__ zb, size_t zStrZ,
             const float* __restrict__ g, const float* __restrict__ b,
             float* __restrict__ outc, int n) {
    int row = blockIdx.x * 4 + (threadIdx.x >> 6);
    if (row >= n) return;
    int lane = threadIdx.x & 63, c0 = lane * 4;
    float g0 = g[c0], g1 = g[c0 + 1], g2 = g[c0 + 2], g3 = g[c0 + 3];
    float b0 = b[c0], b1 = b[c0 + 1], b2 = b[c0 + 2], b3 = b[c0 + 3];
    float o0 = 0.f, o1 = 0.f, o2 = 0.f, o3 = 0.f;
    #pragma unroll
    for (int r = 0; r < NREL; ++r) {
        ushort4v v = *(const ushort4v*)(zb + r * zStrZ + (size_t)row * 256 + c0);
        float vx = bf2f(v.x), vy = bf2f(v.y), vz = bf2f(v.z), vw = bf2f(v.w);
        float s = vx + vy + vz + vw;
        #pragma unroll
        for (int off = 1; off < 64; off <<= 1) s += __shfl_xor(s, off, 64);
        float mean = s * (1.0f / 256.0f);
        float dx = vx - mean, dy = vy - mean, dz = vz - mean, dw = vw - mean;
        float qs = dx * dx + dy * dy + dz * dz + dw * dw;
        #pragma unroll
        for (int off = 1; off < 64; off <<= 1) qs += __shfl_xor(qs, off, 64);
        float rstd = rsqrtf(qs * (1.0f / 256.0f) + 1e-5f);
        o0 += 0.25f * (dx * rstd * g0 + b0);
        o1 += 0.25f * (dy * rstd * g1 + b1);
        o2 += 0.25f * (dz * rstd * g2 + b2);
        o3 += 0.25f * (dw * rstd * g3 + b3);
    }
    float4 o; o.x = o0; o.y = o1; o.z = o2; o.w = o3;
    *(float4*)(outc + (size_t)row * 256 + c0) = o;
}

// ------------------------------ host ---------------------------------------

extern "C" void kernel_launch(void* const* d_in, const int* in_sizes, int n_in,
                              void* d_out, int out_size, void* d_ws, size_t ws_size,
                              hipStream_t stream) {
    const float* x      = (const float*)d_in[0];
    const int*   tri    = (const int*)d_in[1];
    const float* nodeW  = (const float*)d_in[3];
    const float* triW   = (const float*)d_in[4];
    const float* resW   = (const float*)d_in[5];
    const float* gateW  = (const float*)d_in[6];
    const float* gate_b = (const float*)d_in[7];
    const float* inW    = (const float*)d_in[8];
    const float* in_b   = (const float*)d_in[9];
    const float* outW   = (const float*)d_in[10];
    const float* out_b  = (const float*)d_in[11];
    const float* ln1g   = (const float*)d_in[12];
    const float* ln1b   = (const float*)d_in[13];
    const float* lin1W  = (const float*)d_in[14];
    const float* lin1b  = (const float*)d_in[15];
    const float* lin2W  = (const float*)d_in[16];
    const float* lin2b  = (const float*)d_in[17];
    const float* ln2g   = (const float*)d_in[18];
    const float* ln2b   = (const float*)d_in[19];
    float* out = (float*)d_out;

    // ---------------- persistent workspace ----------------
    char* ws = (char*)d_ws;
    size_t off = 0;
    auto alloc = [&](size_t bytes) -> char* {
        char* p = ws + off; off += (bytes + 255) & ~(size_t)255; return p;
    };
    ushortT* accAll  = (ushortT*)alloc((size_t)NREL * NPAD * 256 * 2);  // 205 MB
    ushortT* xall_b  = (ushortT*)alloc((size_t)NPAD * 256 * 2);         // 51 MB
    ushortT* wcomb   = (ushortT*)alloc((size_t)NREL * 65536 * 2);
    ushortT* xgW_b   = (ushortT*)alloc((size_t)131072 * 2);
    ushortT* gateW_b = (ushortT*)alloc((size_t)131072 * 2);
    ushortT* inW_b   = (ushortT*)alloc((size_t)131072 * 2);             // qk rows only
    ushortT* wvo_b   = (ushortT*)alloc((size_t)131072 * 2);
    ushortT* lin1_bf = (ushortT*)alloc((size_t)131072 * 2);
    ushortT* lin2_bf = (ushortT*)alloc((size_t)131072 * 2);
    float*   bvo     = (float*)  alloc((size_t)512 * 4);
    size_t persist = off;
    size_t scratch = (ws_size > persist) ? (ws_size - persist) : 0;
    char* S = ws + persist;

    // scatter-phase scratch (dead before chunk phase): batched CSR + meanx
    int*     cnt4  = (int*)(S);                            // 4*NPAD
    int*     ptr4  = cnt4 + 4 * NPAD;
    int*     cur4  = ptr4 + 4 * NPAD;
    int*     bsum4 = cur4 + 4 * NPAD;                      // 4*512
    int*     bpre4 = bsum4 + 4 * 512;
    int*     adj4  = bpre4 + 4 * 512;                      // 4*3*NTRI
    size_t csrBytes = ((char*)(adj4 + (size_t)4 * 3 * NTRI) - S + 255) & ~(size_t)255;
    const size_t mxBytes = (size_t)NTRI * 256 * 2;         // 77 MB
    if (scratch < csrBytes + mxBytes + 65536) return;
    ushortT* mxbf = (ushortT*)(S + csrBytes);

    // chunk scratch: 9344 B/row (phase-aliased layout, zb in bf16)
    const size_t ROWB = 9344;
    int TT = (NNODES + 127) / 128;              // 782
    int tpcMax = (int)(scratch / (ROWB * 128));
    if (tpcMax < 1) return;
    if (tpcMax > TT) tpcMax = TT;
    const int nchunks = (TT + tpcMax - 1) / tpcMax;
    const int tpc = (TT + nchunks - 1) / nchunks;       // balanced chunks
    const size_t NcPad = (size_t)tpc * 128;

    // chunk layout (byte-offset/row):
    //   A: xg@0 (1024) | ubf4@1024 (2048) | h4@3072 (2048)
    //   B: qk4@5120 (4096) | Aw@9216 (128) | vo4 alias qk4 | x1@0 (2048)
    //   C: ffg@2048 (4096) | zbb@6144 (2048, bf16)
    ushortT* xg   = (ushortT*)(S);
    ushortT* ubf4 = (ushortT*)(S + 1024 * NcPad);
    ushortT* h4   = (ushortT*)(S + 3072 * NcPad);
    ushortT* qk4  = (ushortT*)(S + 5120 * NcPad);
    ushortT* vo4  = qk4;
    ushortT* x1   = (ushortT*)(S);
    ushortT* ffg  = (ushortT*)(S + 2048 * NcPad);
    ushortT* zbb  = (ushortT*)(S + 6144 * NcPad);
    float*   Aw   = (float*)  (S + 9216 * NcPad);

    // ---------------- weights to bf16 + folds ----------------
    cvt_f32_bf16<<<2048, 256, 0, stream>>>(x, xall_b, NNODES * 64);
    cvt_f32_bf16<<<64, 256, 0, stream>>>(gateW, gateW_b, 131072 / 4);
    cvt_f32_bf16<<<64, 256, 0, stream>>>(inW,   inW_b,   131072 / 4);
    cvt_f32_bf16<<<64, 256, 0, stream>>>(lin1W, lin1_bf, 131072 / 4);
    cvt_f32_bf16<<<64, 256, 0, stream>>>(lin2W, lin2_bf, 131072 / 4);
    pack_xg<<<512, 256, 0, stream>>>(resW, gateW, xgW_b);
    pack_wvo<<<512, 256, 0, stream>>>(outW, inW, wvo_b);
    calc_bvo<<<2, 256, 0, stream>>>(outW, in_b, bvo);
    wcomb_kernel<<<1024, 256, 0, stream>>>(nodeW, triW, wcomb);

    // ---------------- scatter phase: partitioned CSR, per-relation gather --
    const int NB = (NNODES + 255) / 256;        // 391 scan blocks
    const int N3B = (3 * NTRI + 255) / 256;
    (void)hipMemsetAsync(cnt4, 0, (size_t)4 * NPAD * 4, stream);
    k_count8<<<dim3(8 * N3B, 4), 256, 0, stream>>>(tri, cnt4, 3 * NTRI);
    k_scan1<<<dim3(NB, 4), 256, 0, stream>>>(cnt4, ptr4, bsum4, NNODES);
    k_scan2<<<4, 64, 0, stream>>>(bsum4, bpre4, NB);
    k_scan3<<<dim3(NB, 4), 256, 0, stream>>>(bpre4, ptr4, cur4, NNODES);
    k_fill8<<<dim3(8 * N3B, 4), 256, 0, stream>>>(tri, cur4, adj4, 3 * NTRI, NTRI);
    for (int r = 0; r < NREL; ++r) {
        const int* trir = tri + (size_t)r * 3 * NTRI;
        k_meanx<<<(NTRI + 3) / 4, 256, 0, stream>>>(trir, xall_b, mxbf, NTRI);
        k_gather<<<(NNODES + 3) / 4, 256, 0, stream>>>(
            ptr4 + (size_t)r * NPAD, cnt4 + (size_t)r * NPAD,
            adj4 + (size_t)r * 3 * NTRI, mxbf,
            accAll + (size_t)r * NPAD * 256, NNODES);
    }

    // ---------------- chunked main pipeline ----------------
    for (int ci = 0; ci < nchunks; ++ci) {
        const int rows0 = ci * tpc * 128;
        int mact = NNODES - rows0;
        if (mact <= 0) break;
        if (mact > tpc * 128) mact = tpc * 128;
        const int tiles = (mact + 127) / 128;
        const dim3 g2z(2, tiles, NREL), g4z(4, tiles, NREL);
        const int nwblk = (mact + 3) / 4;
        float* outc = out + (size_t)rows0 * 256;
        const ushortT* xbf = xall_b + (size_t)rows0 * 256;

        // xg = [x@res_W.T | x@gate_W[:, :D].T]  (N=512, packed weight)
        gemm_bt<M_BF16><<<dim3(4, tiles), 256, 0, stream>>>(xbf, 256, 0, xgW_b, 256, 0, mact, 256,
            xg, 512, 0, nullptr, nullptr, nullptr, 0, nullptr, 0);
        // u[r] = elu(acc[r] @ W_comb[r].T)
        gemm_bt<M_ELU><<<g2z, 256, 0, stream>>>(
            accAll + (size_t)rows0 * 256, 256, (size_t)NPAD * 256,
            wcomb, 256, 65536, mact, 256,
            ubf4, 256, 256 * NcPad, nullptr, nullptr, nullptr, 0, nullptr, 0);
        // a = sigmoid(u@gW2.T + Gx + b); h = tanh(u)*a + xres*(1-a)
        gemm_bt<M_GATE><<<g2z, 256, 0, stream>>>(
            ubf4, 256, 256 * NcPad, gateW_b + 256, 512, 0, mact, 256,
            h4, 256, 256 * NcPad, gate_b, xg + 256, xg, 512, nullptr, 0);
        // qk[r] = h[r] @ in_W[0:512].T + b
        gemm_bt<M_QKV><<<g4z, 256, 0, stream>>>(
            h4, 256, 256 * NcPad, inW_b, 256, 0, mact, 256,
            qk4, 512, 512 * NcPad, in_b, nullptr, nullptr, 0, nullptr, 0);
        attn_score<<<nwblk, 256, 0, stream>>>(qk4, 512 * NcPad, Aw, mact);
        // vo[r] = h[r] @ Wvo.T + bvo   (out_W folded; qk region dead)
        gemm_bt<M_QKV><<<g4z, 256, 0, stream>>>(
            h4, 256, 256 * NcPad, wvo_b, 256, 0, mact, 256,
            vo4, 512, 512 * NcPad, bvo, nullptr, nullptr, 0, nullptr, 0);
        // z = h + combine(A, vo) + out_b ; x1 = LN1(z)   (fused, in-register)
        attn_combine_ln1<<<nwblk, 256, 0, stream>>>(vo4, 512 * NcPad, h4, 256 * NcPad,
            Aw, out_b, ln1g, ln1b, x1, 256 * NcPad, mact);
        // ffg = gelu(x1 @ lin1_W.T + b)
        gemm_bt<M_GELU><<<g4z, 256, 0, stream>>>(x1, 256, 256 * NcPad, lin1_bf, 256, 0, mact, 256,
            ffg, 512, 512 * NcPad, lin1b, nullptr, nullptr, 0, nullptr, 0);
        // z = x1 + ffg @ lin2_W.T + b   (bf16 out)
        gemm_bt<M_RES><<<g2z, 256, 0, stream>>>(ffg, 512, 512 * NcPad, lin2_bf, 512, 0, mact, 512,
            zbb, 256, 256 * NcPad, lin2b, nullptr, nullptr, 0, x1, 256 * NcPad);
        // out = 0.25 * sum_r LN2(z[r])
        ln2_out<<<nwblk, 256, 0, stream>>>(zbb, 256 * NcPad, ln2g, ln2b, outc, mact);
    }
}